// Round 1
// baseline (1441.372 us; speedup 1.0000x reference)
//
#include <hip/hip_runtime.h>
#include <hip/hip_bf16.h>
#include <stdint.h>

#define Bv 8
#define Nv 4096
#define Cv 256
#define Kv 16
#define RPEv 64

static __device__ __forceinline__ float bf2f(unsigned int u16) {
    union { unsigned int i; float f; } v; v.i = u16 << 16; return v.f;
}
static __device__ __forceinline__ unsigned short f2bf(float f) {
    union { float f; unsigned int i; } v; v.f = f;
    unsigned int x = v.i;
    return (unsigned short)((x + 0x7fffu + ((x >> 16) & 1u)) >> 16);
}

// ---------------- K0: tiny prep (w2sum = colsum over C of W2, b2sum) -------
__global__ void prep_kernel(const float* __restrict__ W2, const float* __restrict__ b2,
                            float* __restrict__ w2sum, float* __restrict__ b2sum) {
    const int u = threadIdx.x;
    if (u < RPEv) {
        float s = 0.f;
        for (int c = 0; c < Cv; ++c) s += W2[u * Cv + c];
        w2sum[u] = s;
    }
    if (u == 0) {
        float s = 0.f;
        for (int c = 0; c < Cv; ++c) s += b2[c];
        *b2sum = s;
    }
}

// ---------------- K1: fused dual-LayerNorm + QKV GEMV (8 rows / block) -----
__global__ __launch_bounds__(256) void ln_qkv_kernel(
    const float* __restrict__ x,
    const float* __restrict__ Wq, const float* __restrict__ Wk, const float* __restrict__ Wv,
    const float* __restrict__ gq, const float* __restrict__ bq,
    const float* __restrict__ gkv, const float* __restrict__ bkv,
    unsigned short* __restrict__ qo, unsigned short* __restrict__ ko,
    unsigned short* __restrict__ vo)
{
    __shared__ float xq_lds[8][Cv];
    __shared__ float xkv_lds[8][Cv];
    const int tid = threadIdx.x;
    const long r0 = (long)blockIdx.x * 8;
    const int row = tid >> 5;          // 32 threads per row
    const int c0 = (tid & 31) * 8;     // 8 consecutive channels each
    const float* xr = x + (r0 + row) * Cv + c0;
    float xv[8];
    *(float4*)&xv[0] = *(const float4*)xr;
    *(float4*)&xv[4] = *(const float4*)(xr + 4);
    float s = 0.f, s2 = 0.f;
#pragma unroll
    for (int i = 0; i < 8; ++i) { s += xv[i]; s2 = fmaf(xv[i], xv[i], s2); }
#pragma unroll
    for (int m = 16; m >= 1; m >>= 1) { s += __shfl_xor(s, m); s2 += __shfl_xor(s2, m); }
    const float mean = s * (1.f / Cv);
    const float var = fmaf(-mean, mean, s2 * (1.f / Cv));
    const float rs = rsqrtf(fmaxf(var, 0.f) + 1e-5f);
#pragma unroll
    for (int i = 0; i < 8; ++i) {
        const int c = c0 + i;
        const float xh = (xv[i] - mean) * rs;
        xq_lds[row][c]  = fmaf(xh, gq[c],  bq[c]);
        xkv_lds[row][c] = fmaf(xh, gkv[c], bkv[c]);
    }
    __syncthreads();
    const int j = tid;
    float aq[8] = {}, ak[8] = {}, av[8] = {};
    for (int c = 0; c < Cv; c += 4) {
        float wq_[4], wk_[4], wv_[4];
#pragma unroll
        for (int i = 0; i < 4; ++i) {
            wq_[i] = Wq[(c + i) * Cv + j];
            wk_[i] = Wk[(c + i) * Cv + j];
            wv_[i] = Wv[(c + i) * Cv + j];
        }
#pragma unroll
        for (int r = 0; r < 8; ++r) {
            const float4 a  = *(const float4*)&xq_lds[r][c];
            const float4 bb = *(const float4*)&xkv_lds[r][c];
            aq[r] = fmaf(a.w,  wq_[3], fmaf(a.z,  wq_[2], fmaf(a.y,  wq_[1], fmaf(a.x,  wq_[0], aq[r]))));
            ak[r] = fmaf(bb.w, wk_[3], fmaf(bb.z, wk_[2], fmaf(bb.y, wk_[1], fmaf(bb.x, wk_[0], ak[r]))));
            av[r] = fmaf(bb.w, wv_[3], fmaf(bb.z, wv_[2], fmaf(bb.y, wv_[1], fmaf(bb.x, wv_[0], av[r]))));
        }
    }
#pragma unroll
    for (int r = 0; r < 8; ++r) {
        qo[(r0 + r) * Cv + j] = f2bf(aq[r]);
        ko[(r0 + r) * Cv + j] = f2bf(ak[r]);
        vo[(r0 + r) * Cv + j] = f2bf(av[r]);
    }
}

// ---------------- K2: brute-force kNN, fp32 top-20 scan + f64 re-rank ------
__global__ __launch_bounds__(128) void knn_kernel(
    const float* __restrict__ pos, int* __restrict__ idx_out)
{
    __shared__ float pxs[Nv], pys[Nv], pzs[Nv], a2s[Nv];
    const int tid = threadIdx.x;
    const int q = blockIdx.x * 128 + tid;   // global query index
    const int b = q >> 12;
    const int n = q & (Nv - 1);
    const float* pb = pos + (long)b * Nv * 3;
    for (int i = tid; i < Nv; i += 128) {
        const float px = pb[i * 3 + 0], py = pb[i * 3 + 1], pz = pb[i * 3 + 2];
        pxs[i] = px; pys[i] = py; pzs[i] = pz;
        a2s[i] = fmaf(px, px, fmaf(py, py, pz * pz));
    }
    __syncthreads();
    const float qx = pxs[n], qy = pys[n], qz = pzs[n], a2q = a2s[n];
    // sorted ascending chain of u64 keys: (f32 dist bits << 32) | idx
    unsigned long long ch[20];
#pragma unroll
    for (int i = 0; i < 20; ++i) ch[i] = ~0ull;
    for (int jj = 0; jj < Nv; ++jj) {
        const float dot = fmaf(qx, pxs[jj], fmaf(qy, pys[jj], qz * pzs[jj]));
        float d = fmaf(-2.f, dot, a2q + a2s[jj]);
        d = fmaxf(d, 0.f);
        if (jj == n) d = 0.f;
        const unsigned long long kk =
            ((unsigned long long)__float_as_uint(d) << 32) | (unsigned)jj;
        if (kk < ch[19]) {
            unsigned long long c = kk;
#pragma unroll
            for (int i = 0; i < 20; ++i) {
                const unsigned long long lo = (ch[i] < c) ? ch[i] : c;
                c = ch[i] ^ c ^ lo;   // max
                ch[i] = lo;
            }
        }
    }
    // exact float64 re-rank of the 20 survivors -> top-16
    const double a2qd = (double)qx * qx + (double)qy * qy + (double)qz * qz;
    double dd[20]; int ii[20];
#pragma unroll
    for (int i = 0; i < 20; ++i) {
        const int jj = (int)(unsigned)ch[i];
        ii[i] = jj;
        const double cx = pxs[jj], cy = pys[jj], cz = pzs[jj];
        const double ddot = (double)qx * cx + (double)qy * cy + (double)qz * cz;
        const double a2cd = cx * cx + cy * cy + cz * cz;
        double dv = a2qd + a2cd - 2.0 * ddot;
        dv = (dv < 0.0) ? 0.0 : dv;
        if (jj == n) dv = 0.0;
        dd[i] = dv;
    }
#pragma unroll
    for (int s = 0; s < Kv; ++s) {
#pragma unroll
        for (int t = s + 1; t < 20; ++t) {
            const bool sw = (dd[t] < dd[s]) || (dd[t] == dd[s] && ii[t] < ii[s]);
            const double mn = sw ? dd[t] : dd[s];
            const double mx = sw ? dd[s] : dd[t];
            const int mni = sw ? ii[t] : ii[s];
            const int mxi = sw ? ii[s] : ii[t];
            dd[s] = mn; dd[t] = mx; ii[s] = mni; ii[t] = mxi;
        }
        idx_out[(long)q * Kv + s] = ii[s];
    }
}

// ---------------- K3: gather + attention + RPE bias + output projection ----
__global__ __launch_bounds__(256) void attn_kernel(
    const unsigned short* __restrict__ qb, const unsigned short* __restrict__ kb,
    const unsigned short* __restrict__ vb, const int* __restrict__ idx,
    const float* __restrict__ pos, const float* __restrict__ W1,
    const float* __restrict__ b1, const float* __restrict__ w2sum,
    const float* __restrict__ b2sum, const float* __restrict__ Wp,
    const float* __restrict__ bp, float* __restrict__ out)
{
    __shared__ float q_lds[8][Cv];
    __shared__ float o_lds[8][Cv];
    __shared__ float lg[8][Kv];
    __shared__ float wgt[8][Kv];
    __shared__ int idx_l[8][Kv];
    __shared__ float W1l[3 * RPEv];
    __shared__ float b1l[RPEv], w2s[RPEv];
    __shared__ float posq[24];
    __shared__ float b2s_l;

    const int tid = threadIdx.x;
    const long r0 = (long)blockIdx.x * 8;   // 8 query rows per block
    const int bq = (int)(r0 >> 12);

    {
        float* ql = &q_lds[0][0];
        for (int i = tid; i < 8 * Cv; i += 256) ql[i] = bf2f(qb[r0 * Cv + i]);
    }
    if (tid < 128) ((int*)idx_l)[tid] = idx[r0 * Kv + tid];
    if (tid < 3 * RPEv) W1l[tid] = W1[tid];
    if (tid < RPEv) { b1l[tid] = b1[tid]; w2s[tid] = w2sum[tid]; }
    if (tid < 24) posq[tid] = pos[r0 * 3 + tid];
    if (tid == 0) b2s_l = *b2sum;
    __syncthreads();

    const int g = tid >> 4, l = tid & 15;   // 16 groups x 16 lanes
    for (int r = 0; r < 8; ++r) {
        const int nb = idx_l[r][g];
        const long gi = (long)bq * Nv + nb;
        const unsigned short* kr = kb + gi * Cv + l * 16;
        const float* qq = &q_lds[r][l * 16];
        const uint4 kA = *(const uint4*)kr;
        const uint4 kB = *(const uint4*)(kr + 8);
        float part = 0.f;
        part = fmaf(qq[0],  bf2f(kA.x & 0xffffu), part);
        part = fmaf(qq[1],  bf2f(kA.x >> 16),     part);
        part = fmaf(qq[2],  bf2f(kA.y & 0xffffu), part);
        part = fmaf(qq[3],  bf2f(kA.y >> 16),     part);
        part = fmaf(qq[4],  bf2f(kA.z & 0xffffu), part);
        part = fmaf(qq[5],  bf2f(kA.z >> 16),     part);
        part = fmaf(qq[6],  bf2f(kA.w & 0xffffu), part);
        part = fmaf(qq[7],  bf2f(kA.w >> 16),     part);
        part = fmaf(qq[8],  bf2f(kB.x & 0xffffu), part);
        part = fmaf(qq[9],  bf2f(kB.x >> 16),     part);
        part = fmaf(qq[10], bf2f(kB.y & 0xffffu), part);
        part = fmaf(qq[11], bf2f(kB.y >> 16),     part);
        part = fmaf(qq[12], bf2f(kB.z & 0xffffu), part);
        part = fmaf(qq[13], bf2f(kB.z >> 16),     part);
        part = fmaf(qq[14], bf2f(kB.w & 0xffffu), part);
        part = fmaf(qq[15], bf2f(kB.w >> 16),     part);
        // relative-position MLP, channel-summed: relu(rel@W1+b1) . w2sum
        const float rx = posq[r * 3 + 0] - pos[gi * 3 + 0];
        const float ry = posq[r * 3 + 1] - pos[gi * 3 + 1];
        const float rz = posq[r * 3 + 2] - pos[gi * 3 + 2];
#pragma unroll
        for (int u4 = 0; u4 < 4; ++u4) {
            const int u = l * 4 + u4;
            float h = fmaf(rx, W1l[u], fmaf(ry, W1l[RPEv + u], fmaf(rz, W1l[2 * RPEv + u], b1l[u])));
            h = fmaxf(h, 0.f);
            part = fmaf(h, w2s[u], part);
        }
        part += __shfl_xor(part, 8);
        part += __shfl_xor(part, 4);
        part += __shfl_xor(part, 2);
        part += __shfl_xor(part, 1);
        if (l == 0) lg[r][g] = (part + b2s_l) * 0.0625f;
    }
    __syncthreads();
    if (tid < 128) {
        const int rr = tid >> 4, gg = tid & 15;
        const float v = lg[rr][gg];
        float m = v;
        m = fmaxf(m, __shfl_xor(m, 8)); m = fmaxf(m, __shfl_xor(m, 4));
        m = fmaxf(m, __shfl_xor(m, 2)); m = fmaxf(m, __shfl_xor(m, 1));
        const float e = __expf(v - m);
        float ssum = e;
        ssum += __shfl_xor(ssum, 8); ssum += __shfl_xor(ssum, 4);
        ssum += __shfl_xor(ssum, 2); ssum += __shfl_xor(ssum, 1);
        wgt[rr][gg] = e / ssum;
    }
    __syncthreads();
    {
        const int c = tid;
        for (int r = 0; r < 8; ++r) {
            float acc = 0.f;
#pragma unroll
            for (int t = 0; t < Kv; ++t) {
                const long gi = (long)bq * Nv + idx_l[r][t];
                acc = fmaf(wgt[r][t], bf2f((unsigned)vb[gi * Cv + c]), acc);
            }
            o_lds[r][c] = acc;
        }
    }
    __syncthreads();
    {
        const int j = tid;
        float accf[8] = {0.f, 0.f, 0.f, 0.f, 0.f, 0.f, 0.f, 0.f};
        for (int c = 0; c < Cv; c += 4) {
            const float wp0 = Wp[(c + 0) * Cv + j];
            const float wp1 = Wp[(c + 1) * Cv + j];
            const float wp2 = Wp[(c + 2) * Cv + j];
            const float wp3 = Wp[(c + 3) * Cv + j];
#pragma unroll
            for (int r = 0; r < 8; ++r) {
                const float4 o4 = *(const float4*)&o_lds[r][c];
                accf[r] = fmaf(o4.x, wp0, fmaf(o4.y, wp1, fmaf(o4.z, wp2, fmaf(o4.w, wp3, accf[r]))));
            }
        }
        const float bpj = bp[j];
#pragma unroll
        for (int r = 0; r < 8; ++r)
            out[(r0 + r) * Cv + j] = accf[r] + bpj;
    }
}

extern "C" void kernel_launch(void* const* d_in, const int* in_sizes, int n_in,
                              void* d_out, int out_size, void* d_ws, size_t ws_size,
                              hipStream_t stream) {
    (void)in_sizes; (void)n_in; (void)out_size; (void)ws_size;
    const float* x      = (const float*)d_in[0];
    const float* pos    = (const float*)d_in[1];
    const float* Wq     = (const float*)d_in[2];
    const float* Wk     = (const float*)d_in[3];
    const float* Wv     = (const float*)d_in[4];
    const float* W1     = (const float*)d_in[5];
    const float* b1     = (const float*)d_in[6];
    const float* W2     = (const float*)d_in[7];
    const float* b2     = (const float*)d_in[8];
    const float* Wp     = (const float*)d_in[9];
    const float* bp     = (const float*)d_in[10];
    const float* gq     = (const float*)d_in[11];
    const float* betaq  = (const float*)d_in[12];
    const float* gkv    = (const float*)d_in[13];
    const float* betakv = (const float*)d_in[14];
    float* out = (float*)d_out;

    char* ws = (char*)d_ws;
    unsigned short* qb = (unsigned short*)(ws);               // 32768*256*2 = 16 MiB
    unsigned short* kb = (unsigned short*)(ws + 16777216);
    unsigned short* vb = (unsigned short*)(ws + 33554432);
    int*   idx   = (int*)  (ws + 50331648);                   // 32768*16*4 = 2 MiB
    float* w2sum = (float*)(ws + 52428800);                   // 64 floats
    float* b2sum = (float*)(ws + 52429056);                   // 1 float

    hipLaunchKernelGGL(prep_kernel, dim3(1), dim3(64), 0, stream, W2, b2, w2sum, b2sum);
    hipLaunchKernelGGL(ln_qkv_kernel, dim3(4096), dim3(256), 0, stream,
                       x, Wq, Wk, Wv, gq, betaq, gkv, betakv, qb, kb, vb);
    hipLaunchKernelGGL(knn_kernel, dim3(256), dim3(128), 0, stream, pos, idx);
    hipLaunchKernelGGL(attn_kernel, dim3(4096), dim3(256), 0, stream,
                       qb, kb, vb, idx, pos, W1, b1, w2sum, b2sum, Wp, bp, out);
}

// Round 2
// 614.733 us; speedup vs baseline: 2.3447x; 2.3447x over previous
//
#include <hip/hip_runtime.h>
#include <hip/hip_bf16.h>
#include <stdint.h>

#define Bv 8
#define Nv 4096
#define Cv 256
#define Kv 16
#define RPEv 64

static __device__ __forceinline__ float bf2f(unsigned int u16) {
    union { unsigned int i; float f; } v; v.i = u16 << 16; return v.f;
}
static __device__ __forceinline__ unsigned short f2bf(float f) {
    union { float f; unsigned int i; } v; v.f = f;
    unsigned int x = v.i;
    return (unsigned short)((x + 0x7fffu + ((x >> 16) & 1u)) >> 16);
}
static __device__ __forceinline__ unsigned int umin32(unsigned int a, unsigned int b) { return a < b ? a : b; }
static __device__ __forceinline__ unsigned int umax32(unsigned int a, unsigned int b) { return a > b ? a : b; }

// ---------------- K0: tiny prep (w2sum = colsum over C of W2, b2sum) -------
__global__ void prep_kernel(const float* __restrict__ W2, const float* __restrict__ b2,
                            float* __restrict__ w2sum, float* __restrict__ b2sum) {
    const int u = threadIdx.x;
    if (u < RPEv) {
        float s = 0.f;
        for (int c = 0; c < Cv; ++c) s += W2[u * Cv + c];
        w2sum[u] = s;
    }
    if (u == 0) {
        float s = 0.f;
        for (int c = 0; c < Cv; ++c) s += b2[c];
        *b2sum = s;
    }
}

// ---------------- K1: fused dual-LayerNorm + QKV GEMV (8 rows / block) -----
__global__ __launch_bounds__(256) void ln_qkv_kernel(
    const float* __restrict__ x,
    const float* __restrict__ Wq, const float* __restrict__ Wk, const float* __restrict__ Wv,
    const float* __restrict__ gq, const float* __restrict__ bq,
    const float* __restrict__ gkv, const float* __restrict__ bkv,
    unsigned short* __restrict__ qo, unsigned short* __restrict__ ko,
    unsigned short* __restrict__ vo)
{
    __shared__ float xq_lds[8][Cv];
    __shared__ float xkv_lds[8][Cv];
    const int tid = threadIdx.x;
    const long r0 = (long)blockIdx.x * 8;
    const int row = tid >> 5;          // 32 threads per row
    const int c0 = (tid & 31) * 8;     // 8 consecutive channels each
    const float* xr = x + (r0 + row) * Cv + c0;
    float xv[8];
    *(float4*)&xv[0] = *(const float4*)xr;
    *(float4*)&xv[4] = *(const float4*)(xr + 4);
    float s = 0.f, s2 = 0.f;
#pragma unroll
    for (int i = 0; i < 8; ++i) { s += xv[i]; s2 = fmaf(xv[i], xv[i], s2); }
#pragma unroll
    for (int m = 16; m >= 1; m >>= 1) { s += __shfl_xor(s, m); s2 += __shfl_xor(s2, m); }
    const float mean = s * (1.f / Cv);
    const float var = fmaf(-mean, mean, s2 * (1.f / Cv));
    const float rs = rsqrtf(fmaxf(var, 0.f) + 1e-5f);
#pragma unroll
    for (int i = 0; i < 8; ++i) {
        const int c = c0 + i;
        const float xh = (xv[i] - mean) * rs;
        xq_lds[row][c]  = fmaf(xh, gq[c],  bq[c]);
        xkv_lds[row][c] = fmaf(xh, gkv[c], bkv[c]);
    }
    __syncthreads();
    const int j = tid;
    float aq[8] = {}, ak[8] = {}, av[8] = {};
    for (int c = 0; c < Cv; c += 4) {
        float wq_[4], wk_[4], wv_[4];
#pragma unroll
        for (int i = 0; i < 4; ++i) {
            wq_[i] = Wq[(c + i) * Cv + j];
            wk_[i] = Wk[(c + i) * Cv + j];
            wv_[i] = Wv[(c + i) * Cv + j];
        }
#pragma unroll
        for (int r = 0; r < 8; ++r) {
            const float4 a  = *(const float4*)&xq_lds[r][c];
            const float4 bb = *(const float4*)&xkv_lds[r][c];
            aq[r] = fmaf(a.w,  wq_[3], fmaf(a.z,  wq_[2], fmaf(a.y,  wq_[1], fmaf(a.x,  wq_[0], aq[r]))));
            ak[r] = fmaf(bb.w, wk_[3], fmaf(bb.z, wk_[2], fmaf(bb.y, wk_[1], fmaf(bb.x, wk_[0], ak[r]))));
            av[r] = fmaf(bb.w, wv_[3], fmaf(bb.z, wv_[2], fmaf(bb.y, wv_[1], fmaf(bb.x, wv_[0], av[r]))));
        }
    }
#pragma unroll
    for (int r = 0; r < 8; ++r) {
        qo[(r0 + r) * Cv + j] = f2bf(aq[r]);
        ko[(r0 + r) * Cv + j] = f2bf(ak[r]);
        vo[(r0 + r) * Cv + j] = f2bf(av[r]);
    }
}

// ---------------- K2: kNN v2 — 4 threads/query segmented scan --------------
// u32 keys (20-bit truncated f32 dist | 12-bit idx), pair pre-min insert,
// exact f64 re-rank of the 4x20 union, top-16 set selection.
__global__ __launch_bounds__(256) void knn_kernel(
    const float* __restrict__ pos, int* __restrict__ idx_out)
{
    __shared__ float4 P4[Nv];                      // 64 KiB: (-2x,-2y,-2z,|p|^2)
    unsigned long long* kbuf = (unsigned long long*)P4;  // aliased after scan: [64][81]

    const int tid = threadIdx.x;
    const int ql = tid >> 2;                 // 0..63 query within block
    const int s  = tid & 3;                  // segment 0..3
    const int q  = blockIdx.x * 64 + ql;     // global query (block never straddles batch)
    const int b  = q >> 12;
    const int n  = q & (Nv - 1);
    const float* pb = pos + (size_t)b * Nv * 3;

    for (int i = tid; i < Nv; i += 256) {
        const float px = pb[3 * i], py = pb[3 * i + 1], pz = pb[3 * i + 2];
        const float a2 = fmaf(px, px, fmaf(py, py, pz * pz));
        P4[i] = make_float4(-2.f * px, -2.f * py, -2.f * pz, a2);
    }
    __syncthreads();

    const float4 self = P4[n];
    const float qx = -0.5f * self.x, qy = -0.5f * self.y, qz = -0.5f * self.z;
    const float a2q = self.w;

    unsigned int ch[20];
#pragma unroll
    for (int i = 0; i < 20; ++i) ch[i] = 0xFFFFFFFFu;

    const int jbase = s * 1024;
    for (int t = 0; t < 1024; t += 2) {
        const int j = jbase + t;
        const float4 c0 = P4[j];
        const float4 c1 = P4[j + 1];
        const float h0 = fmaf(qx, c0.x, fmaf(qy, c0.y, fmaf(qz, c0.z, c0.w)));
        const float h1 = fmaf(qx, c1.x, fmaf(qy, c1.y, fmaf(qz, c1.z, c1.w)));
        const float d0 = fmaxf(a2q + h0, 0.f);
        const float d1 = fmaxf(a2q + h1, 0.f);
        const unsigned int k0 = (__float_as_uint(d0) & 0xFFFFF000u) | (unsigned)j;
        const unsigned int k1 = (__float_as_uint(d1) & 0xFFFFF000u) | (unsigned)(j + 1);
        const unsigned int klo = umin32(k0, k1);
        const unsigned int khi = umax32(k0, k1);
        if (klo < ch[19]) {
            unsigned int c = klo;
#pragma unroll
            for (int i = 0; i < 20; ++i) {
                const unsigned int lo = umin32(ch[i], c);
                c = umax32(ch[i], c);
                ch[i] = lo;
            }
            if (khi < ch[19]) {
                unsigned int c2 = khi;
#pragma unroll
                for (int i = 0; i < 20; ++i) {
                    const unsigned int lo = umin32(ch[i], c2);
                    c2 = umax32(ch[i], c2);
                    ch[i] = lo;
                }
            }
        }
    }

    // exact f64 re-rank of this thread's 20 survivors (coords exact from -2x staging)
    const double qxd = (double)qx, qyd = (double)qy, qzd = (double)qz;
    const double a2qd = qxd * qxd + qyd * qyd + qzd * qzd;
    unsigned long long kk[20];
#pragma unroll
    for (int i = 0; i < 20; ++i) {
        const int j = (int)(ch[i] & 0xFFFu);
        const float4 cc = P4[j];
        const double cx = (double)(-0.5f * cc.x);
        const double cy = (double)(-0.5f * cc.y);
        const double cz = (double)(-0.5f * cc.z);
        const double a2cd = cx * cx + cy * cy + cz * cz;
        const double ddot = qxd * cx + qyd * cy + qzd * cz;
        double dv = (a2qd + a2cd) - 2.0 * ddot;
        dv = (dv < 0.0) ? 0.0 : dv;
        if (j == n) dv = 0.0;
        union { double d; unsigned long long u; } cv; cv.d = dv;
        kk[i] = (cv.u & ~0xFFFULL) | (unsigned long long)j;
    }
    __syncthreads();   // everyone done reading P4 — safe to alias
#pragma unroll
    for (int i = 0; i < 20; ++i) kbuf[ql * 81 + s * 20 + i] = kk[i];
    __syncthreads();

    if (s == 0) {
        unsigned long long sel[Kv];
#pragma unroll
        for (int i = 0; i < Kv; ++i) sel[i] = ~0ull;
        for (int t = 0; t < 80; ++t) {
            const unsigned long long cand = kbuf[ql * 81 + t];
            if (cand < sel[Kv - 1]) {
                unsigned long long c = cand;
#pragma unroll
                for (int i = 0; i < Kv; ++i) {
                    const unsigned long long lo = (sel[i] < c) ? sel[i] : c;
                    const unsigned long long hi = (sel[i] < c) ? c : sel[i];
                    sel[i] = lo; c = hi;
                }
            }
        }
#pragma unroll
        for (int i = 0; i < Kv; ++i)
            idx_out[(long)q * Kv + i] = (int)(sel[i] & 0xFFFull);
    }
}

// ---------------- K3: gather + attention + RPE bias + output projection ----
__global__ __launch_bounds__(256) void attn_kernel(
    const unsigned short* __restrict__ qb, const unsigned short* __restrict__ kb,
    const unsigned short* __restrict__ vb, const int* __restrict__ idx,
    const float* __restrict__ pos, const float* __restrict__ W1,
    const float* __restrict__ b1, const float* __restrict__ w2sum,
    const float* __restrict__ b2sum, const float* __restrict__ Wp,
    const float* __restrict__ bp, float* __restrict__ out)
{
    __shared__ float q_lds[8][Cv];
    __shared__ float o_lds[8][Cv];
    __shared__ float lg[8][Kv];
    __shared__ float wgt[8][Kv];
    __shared__ int idx_l[8][Kv];
    __shared__ float W1l[3 * RPEv];
    __shared__ float b1l[RPEv], w2s[RPEv];
    __shared__ float posq[24];
    __shared__ float b2s_l;

    const int tid = threadIdx.x;
    const long r0 = (long)blockIdx.x * 8;   // 8 query rows per block
    const int bq = (int)(r0 >> 12);

    {
        float* ql = &q_lds[0][0];
        for (int i = tid; i < 8 * Cv; i += 256) ql[i] = bf2f(qb[r0 * Cv + i]);
    }
    if (tid < 128) ((int*)idx_l)[tid] = idx[r0 * Kv + tid];
    if (tid < 3 * RPEv) W1l[tid] = W1[tid];
    if (tid < RPEv) { b1l[tid] = b1[tid]; w2s[tid] = w2sum[tid]; }
    if (tid < 24) posq[tid] = pos[r0 * 3 + tid];
    if (tid == 0) b2s_l = *b2sum;
    __syncthreads();

    const int g = tid >> 4, l = tid & 15;   // 16 groups x 16 lanes
    for (int r = 0; r < 8; ++r) {
        const int nb = idx_l[r][g];
        const long gi = (long)bq * Nv + nb;
        const unsigned short* kr = kb + gi * Cv + l * 16;
        const float* qq = &q_lds[r][l * 16];
        const uint4 kA = *(const uint4*)kr;
        const uint4 kB = *(const uint4*)(kr + 8);
        float part = 0.f;
        part = fmaf(qq[0],  bf2f(kA.x & 0xffffu), part);
        part = fmaf(qq[1],  bf2f(kA.x >> 16),     part);
        part = fmaf(qq[2],  bf2f(kA.y & 0xffffu), part);
        part = fmaf(qq[3],  bf2f(kA.y >> 16),     part);
        part = fmaf(qq[4],  bf2f(kA.z & 0xffffu), part);
        part = fmaf(qq[5],  bf2f(kA.z >> 16),     part);
        part = fmaf(qq[6],  bf2f(kA.w & 0xffffu), part);
        part = fmaf(qq[7],  bf2f(kA.w >> 16),     part);
        part = fmaf(qq[8],  bf2f(kB.x & 0xffffu), part);
        part = fmaf(qq[9],  bf2f(kB.x >> 16),     part);
        part = fmaf(qq[10], bf2f(kB.y & 0xffffu), part);
        part = fmaf(qq[11], bf2f(kB.y >> 16),     part);
        part = fmaf(qq[12], bf2f(kB.z & 0xffffu), part);
        part = fmaf(qq[13], bf2f(kB.z >> 16),     part);
        part = fmaf(qq[14], bf2f(kB.w & 0xffffu), part);
        part = fmaf(qq[15], bf2f(kB.w >> 16),     part);
        // relative-position MLP, channel-summed: relu(rel@W1+b1) . w2sum
        const float rx = posq[r * 3 + 0] - pos[gi * 3 + 0];
        const float ry = posq[r * 3 + 1] - pos[gi * 3 + 1];
        const float rz = posq[r * 3 + 2] - pos[gi * 3 + 2];
#pragma unroll
        for (int u4 = 0; u4 < 4; ++u4) {
            const int u = l * 4 + u4;
            float h = fmaf(rx, W1l[u], fmaf(ry, W1l[RPEv + u], fmaf(rz, W1l[2 * RPEv + u], b1l[u])));
            h = fmaxf(h, 0.f);
            part = fmaf(h, w2s[u], part);
        }
        part += __shfl_xor(part, 8);
        part += __shfl_xor(part, 4);
        part += __shfl_xor(part, 2);
        part += __shfl_xor(part, 1);
        if (l == 0) lg[r][g] = (part + b2s_l) * 0.0625f;
    }
    __syncthreads();
    if (tid < 128) {
        const int rr = tid >> 4, gg = tid & 15;
        const float v = lg[rr][gg];
        float m = v;
        m = fmaxf(m, __shfl_xor(m, 8)); m = fmaxf(m, __shfl_xor(m, 4));
        m = fmaxf(m, __shfl_xor(m, 2)); m = fmaxf(m, __shfl_xor(m, 1));
        const float e = __expf(v - m);
        float ssum = e;
        ssum += __shfl_xor(ssum, 8); ssum += __shfl_xor(ssum, 4);
        ssum += __shfl_xor(ssum, 2); ssum += __shfl_xor(ssum, 1);
        wgt[rr][gg] = e / ssum;
    }
    __syncthreads();
    {
        const int c = tid;
        for (int r = 0; r < 8; ++r) {
            float acc = 0.f;
#pragma unroll
            for (int t = 0; t < Kv; ++t) {
                const long gi = (long)bq * Nv + idx_l[r][t];
                acc = fmaf(wgt[r][t], bf2f((unsigned)vb[gi * Cv + c]), acc);
            }
            o_lds[r][c] = acc;
        }
    }
    __syncthreads();
    {
        const int j = tid;
        float accf[8] = {0.f, 0.f, 0.f, 0.f, 0.f, 0.f, 0.f, 0.f};
        for (int c = 0; c < Cv; c += 4) {
            const float wp0 = Wp[(c + 0) * Cv + j];
            const float wp1 = Wp[(c + 1) * Cv + j];
            const float wp2 = Wp[(c + 2) * Cv + j];
            const float wp3 = Wp[(c + 3) * Cv + j];
#pragma unroll
            for (int r = 0; r < 8; ++r) {
                const float4 o4 = *(const float4*)&o_lds[r][c];
                accf[r] = fmaf(o4.x, wp0, fmaf(o4.y, wp1, fmaf(o4.z, wp2, fmaf(o4.w, wp3, accf[r]))));
            }
        }
        const float bpj = bp[j];
#pragma unroll
        for (int r = 0; r < 8; ++r)
            out[(r0 + r) * Cv + j] = accf[r] + bpj;
    }
}

extern "C" void kernel_launch(void* const* d_in, const int* in_sizes, int n_in,
                              void* d_out, int out_size, void* d_ws, size_t ws_size,
                              hipStream_t stream) {
    (void)in_sizes; (void)n_in; (void)out_size; (void)ws_size;
    const float* x      = (const float*)d_in[0];
    const float* pos    = (const float*)d_in[1];
    const float* Wq     = (const float*)d_in[2];
    const float* Wk     = (const float*)d_in[3];
    const float* Wv     = (const float*)d_in[4];
    const float* W1     = (const float*)d_in[5];
    const float* b1     = (const float*)d_in[6];
    const float* W2     = (const float*)d_in[7];
    const float* b2     = (const float*)d_in[8];
    const float* Wp     = (const float*)d_in[9];
    const float* bp     = (const float*)d_in[10];
    const float* gq     = (const float*)d_in[11];
    const float* betaq  = (const float*)d_in[12];
    const float* gkv    = (const float*)d_in[13];
    const float* betakv = (const float*)d_in[14];
    float* out = (float*)d_out;

    char* ws = (char*)d_ws;
    unsigned short* qb = (unsigned short*)(ws);               // 32768*256*2 = 16 MiB
    unsigned short* kb = (unsigned short*)(ws + 16777216);
    unsigned short* vb = (unsigned short*)(ws + 33554432);
    int*   idx   = (int*)  (ws + 50331648);                   // 32768*16*4 = 2 MiB
    float* w2sum = (float*)(ws + 52428800);                   // 64 floats
    float* b2sum = (float*)(ws + 52429056);                   // 1 float

    hipLaunchKernelGGL(prep_kernel, dim3(1), dim3(64), 0, stream, W2, b2, w2sum, b2sum);
    hipLaunchKernelGGL(ln_qkv_kernel, dim3(4096), dim3(256), 0, stream,
                       x, Wq, Wk, Wv, gq, betaq, gkv, betakv, qb, kb, vb);
    hipLaunchKernelGGL(knn_kernel, dim3(512), dim3(256), 0, stream, pos, idx);
    hipLaunchKernelGGL(attn_kernel, dim3(4096), dim3(256), 0, stream,
                       qb, kb, vb, idx, pos, W1, b1, w2sum, b2sum, Wp, bp, out);
}

// Round 3
// 417.387 us; speedup vs baseline: 3.4533x; 1.4728x over previous
//
#include <hip/hip_runtime.h>
#include <hip/hip_bf16.h>
#include <stdint.h>

#define Bv 8
#define Nv 4096
#define Cv 256
#define Kv 16
#define RPEv 64

typedef short bf16x8 __attribute__((ext_vector_type(8)));
typedef float f32x4 __attribute__((ext_vector_type(4)));

static __device__ __forceinline__ float bf2f(unsigned int u16) {
    union { unsigned int i; float f; } v; v.i = u16 << 16; return v.f;
}
static __device__ __forceinline__ unsigned short f2bf(float f) {
    union { float f; unsigned int i; } v; v.f = f;
    unsigned int x = v.i;
    return (unsigned short)((x + 0x7fffu + ((x >> 16) & 1u)) >> 16);
}
static __device__ __forceinline__ unsigned int umin32(unsigned int a, unsigned int b) { return a < b ? a : b; }
static __device__ __forceinline__ unsigned int umax32(unsigned int a, unsigned int b) { return a > b ? a : b; }

// ---------------- K0: tiny prep (w2sum = colsum over C of W2, b2sum) -------
__global__ void prep_kernel(const float* __restrict__ W2, const float* __restrict__ b2,
                            float* __restrict__ w2sum, float* __restrict__ b2sum) {
    const int u = threadIdx.x;
    if (u < RPEv) {
        float s = 0.f;
        for (int c = 0; c < Cv; ++c) s += W2[u * Cv + c];
        w2sum[u] = s;
    }
    if (u == 0) {
        float s = 0.f;
        for (int c = 0; c < Cv; ++c) s += b2[c];
        *b2sum = s;
    }
}

// ---------------- K0b: weight transpose-cast -> Bt[768][256] bf16 ----------
// Bt[mat*256 + n][k] = Wmat[k][n]
__global__ __launch_bounds__(256) void wcast_kernel(
    const float* __restrict__ Wq, const float* __restrict__ Wk,
    const float* __restrict__ Wv, unsigned short* __restrict__ Bt)
{
    const int r = blockIdx.x;       // 0..767
    const int t = threadIdx.x;      // k
    const float* W = (r < 256) ? Wq : (r < 512) ? Wk : Wv;
    const int n = r & 255;
    Bt[r * 256 + t] = f2bf(W[t * 256 + n]);
}

// ---------------- K1a: dual LayerNorm + bf16 cast (A matrices) -------------
__global__ __launch_bounds__(256) void ln_cast_kernel(
    const float* __restrict__ x,
    const float* __restrict__ gq, const float* __restrict__ bq,
    const float* __restrict__ gkv, const float* __restrict__ bkv,
    unsigned short* __restrict__ Aq, unsigned short* __restrict__ Akv)
{
    const int tid = threadIdx.x;
    const long r0 = (long)blockIdx.x * 8;
    const int row = tid >> 5;          // 32 threads per row
    const int c0 = (tid & 31) * 8;     // 8 consecutive channels each
    const float* xr = x + (r0 + row) * Cv + c0;
    float xv[8];
    *(float4*)&xv[0] = *(const float4*)xr;
    *(float4*)&xv[4] = *(const float4*)(xr + 4);
    float s = 0.f, s2 = 0.f;
#pragma unroll
    for (int i = 0; i < 8; ++i) { s += xv[i]; s2 = fmaf(xv[i], xv[i], s2); }
#pragma unroll
    for (int m = 16; m >= 1; m >>= 1) { s += __shfl_xor(s, m); s2 += __shfl_xor(s2, m); }
    const float mean = s * (1.f / Cv);
    const float var = fmaf(-mean, mean, s2 * (1.f / Cv));
    const float rs = rsqrtf(fmaxf(var, 0.f) + 1e-5f);
    unsigned int pq[4], pk[4];
#pragma unroll
    for (int i = 0; i < 4; ++i) {
        const int c = c0 + 2 * i;
        const float h0 = (xv[2 * i] - mean) * rs;
        const float h1 = (xv[2 * i + 1] - mean) * rs;
        const unsigned int q0 = f2bf(fmaf(h0, gq[c], bq[c]));
        const unsigned int q1 = f2bf(fmaf(h1, gq[c + 1], bq[c + 1]));
        const unsigned int k0 = f2bf(fmaf(h0, gkv[c], bkv[c]));
        const unsigned int k1 = f2bf(fmaf(h1, gkv[c + 1], bkv[c + 1]));
        pq[i] = q0 | (q1 << 16);
        pk[i] = k0 | (k1 << 16);
    }
    const long off = (r0 + row) * Cv + c0;
    *(uint4*)&Aq[off]  = make_uint4(pq[0], pq[1], pq[2], pq[3]);
    *(uint4*)&Akv[off] = make_uint4(pk[0], pk[1], pk[2], pk[3]);
}

// ---------------- K1b: bf16 MFMA GEMM  C[32768 x 768] = A @ W --------------
// A (K-major bf16): Aq for col-tiles 0-1, Akv for 2-5. Bt is [768][256] K-major.
// 128x128 tile, BK=64, 4 waves (2x2 of 64x64), dbuf LDS, global_load_lds w16,
// XOR-swizzle (chunk ^= row&7) applied on the global source + LDS read side.
__global__ __launch_bounds__(256) void gemm_qkv_kernel(
    const unsigned short* __restrict__ Aq, const unsigned short* __restrict__ Akv,
    const unsigned short* __restrict__ Bt,
    unsigned short* __restrict__ qo, unsigned short* __restrict__ ko,
    unsigned short* __restrict__ vo)
{
    __shared__ unsigned short Albs[2][128 * 64];
    __shared__ unsigned short Blbs[2][128 * 64];

    const int tid = threadIdx.x;
    const int rt = blockIdx.x;          // row tile: 256
    const int ct = blockIdx.y;          // col tile: 6
    const unsigned short* A = (ct < 2) ? Aq : Akv;
    const int mat = ct >> 1;
    unsigned short* outp = (mat == 0) ? qo : (mat == 1) ? ko : vo;
    const int colInMat = (ct & 1) * 128;

    const int wid = tid >> 6, l = tid & 63;
    const int wr = wid >> 1, wc = wid & 1;

    // staging: 1024 16B-chunks per tile = 4 per thread; linear LDS dest,
    // pre-swizzled global source (chunk-in-row ^= row&7)
    int srow[4], scol8[4];
#pragma unroll
    for (int it = 0; it < 4; ++it) {
        const int chunk = it * 256 + tid;
        srow[it] = chunk >> 3;
        scol8[it] = ((chunk & 7) ^ (srow[it] & 7)) * 8;
    }

#define STAGE(buf, ks)                                                                  \
    {                                                                                   \
        _Pragma("unroll")                                                               \
        for (int it = 0; it < 4; ++it) {                                                \
            const unsigned short* ga = A + ((size_t)(rt * 128 + srow[it])) * 256        \
                                         + (ks) * 64 + scol8[it];                       \
            const unsigned short* gb = Bt + ((size_t)(ct * 128 + srow[it])) * 256       \
                                          + (ks) * 64 + scol8[it];                      \
            __builtin_amdgcn_global_load_lds(                                           \
                (const __attribute__((address_space(1))) unsigned int*)(const void*)ga, \
                (__attribute__((address_space(3))) unsigned int*)(void*)                \
                    ((char*)&Albs[buf][0] + (it * 256 + tid) * 16), 16, 0, 0);          \
            __builtin_amdgcn_global_load_lds(                                           \
                (const __attribute__((address_space(1))) unsigned int*)(const void*)gb, \
                (__attribute__((address_space(3))) unsigned int*)(void*)                \
                    ((char*)&Blbs[buf][0] + (it * 256 + tid) * 16), 16, 0, 0);          \
        }                                                                               \
    }

    f32x4 acc[4][4];
#pragma unroll
    for (int m = 0; m < 4; ++m)
#pragma unroll
        for (int n = 0; n < 4; ++n) acc[m][n] = (f32x4){0.f, 0.f, 0.f, 0.f};

    STAGE(0, 0);
    __syncthreads();

    for (int ks = 0; ks < 4; ++ks) {
        const int cur = ks & 1;
        if (ks < 3) STAGE(cur ^ 1, ks + 1);
#pragma unroll
        for (int kk = 0; kk < 2; ++kk) {
            bf16x8 a[4], b[4];
#pragma unroll
            for (int m = 0; m < 4; ++m) {
                const int row = wr * 64 + m * 16 + (l & 15);
                const int byte = row * 128 + ((((kk * 4 + (l >> 4)) * 16)) ^ ((row & 7) << 4));
                a[m] = *(const bf16x8*)((const char*)&Albs[cur][0] + byte);
            }
#pragma unroll
            for (int n = 0; n < 4; ++n) {
                const int row = wc * 64 + n * 16 + (l & 15);
                const int byte = row * 128 + ((((kk * 4 + (l >> 4)) * 16)) ^ ((row & 7) << 4));
                b[n] = *(const bf16x8*)((const char*)&Blbs[cur][0] + byte);
            }
#pragma unroll
            for (int m = 0; m < 4; ++m)
#pragma unroll
                for (int n = 0; n < 4; ++n)
                    acc[m][n] = __builtin_amdgcn_mfma_f32_16x16x32_bf16(a[m], b[n], acc[m][n], 0, 0, 0);
        }
        __syncthreads();
    }

    // C-write: row=(l>>4)*4+j (M), col=l&15 (N)
#pragma unroll
    for (int m = 0; m < 4; ++m) {
#pragma unroll
        for (int n = 0; n < 4; ++n) {
#pragma unroll
            for (int j = 0; j < 4; ++j) {
                const int row = rt * 128 + wr * 64 + m * 16 + (l >> 4) * 4 + j;
                const int col = colInMat + wc * 64 + n * 16 + (l & 15);
                outp[(size_t)row * 256 + col] = f2bf(acc[m][n][j]);
            }
        }
    }
#undef STAGE
}

// ---------------- K2: kNN — 4 threads/query, interleaved segments ----------
// thread s scans j = 8t+s and 8t+s+4 (quad reads 16B-apart -> conflict-free).
// u32 keys (20-bit trunc f32 dist | 12-bit idx), exact f64 re-rank of 4x20.
__global__ __launch_bounds__(256) void knn_kernel(
    const float* __restrict__ pos, int* __restrict__ idx_out)
{
    __shared__ float4 P4[Nv];                      // 64 KiB: (-2x,-2y,-2z,|p|^2)
    unsigned long long* kbuf = (unsigned long long*)P4;  // aliased after scan: [64][81]

    const int tid = threadIdx.x;
    const int ql = tid >> 2;                 // 0..63 query within block
    const int s  = tid & 3;                  // segment 0..3
    const int q  = blockIdx.x * 64 + ql;     // global query
    const int b  = q >> 12;
    const int n  = q & (Nv - 1);
    const float* pb = pos + (size_t)b * Nv * 3;

    for (int i = tid; i < Nv; i += 256) {
        const float px = pb[3 * i], py = pb[3 * i + 1], pz = pb[3 * i + 2];
        const float a2 = fmaf(px, px, fmaf(py, py, pz * pz));
        P4[i] = make_float4(-2.f * px, -2.f * py, -2.f * pz, a2);
    }
    __syncthreads();

    const float4 self = P4[n];
    const float qx = -0.5f * self.x, qy = -0.5f * self.y, qz = -0.5f * self.z;
    const float a2q = self.w;

    unsigned int ch[20];
#pragma unroll
    for (int i = 0; i < 20; ++i) ch[i] = 0xFFFFFFFFu;

    for (int t = 0; t < 512; ++t) {
        const int j0 = 8 * t + s;
        const int j1 = j0 + 4;
        const float4 c0 = P4[j0];
        const float4 c1 = P4[j1];
        const float h0 = fmaf(qx, c0.x, fmaf(qy, c0.y, fmaf(qz, c0.z, c0.w)));
        const float h1 = fmaf(qx, c1.x, fmaf(qy, c1.y, fmaf(qz, c1.z, c1.w)));
        const float d0 = fmaxf(a2q + h0, 0.f);
        const float d1 = fmaxf(a2q + h1, 0.f);
        const unsigned int k0 = (__float_as_uint(d0) & 0xFFFFF000u) | (unsigned)j0;
        const unsigned int k1 = (__float_as_uint(d1) & 0xFFFFF000u) | (unsigned)j1;
        const unsigned int klo = umin32(k0, k1);
        const unsigned int khi = umax32(k0, k1);
        if (klo < ch[19]) {
            unsigned int c = klo;
#pragma unroll
            for (int i = 0; i < 20; ++i) {
                const unsigned int lo = umin32(ch[i], c);
                c = umax32(ch[i], c);
                ch[i] = lo;
            }
            if (khi < ch[19]) {
                unsigned int c2 = khi;
#pragma unroll
                for (int i = 0; i < 20; ++i) {
                    const unsigned int lo = umin32(ch[i], c2);
                    c2 = umax32(ch[i], c2);
                    ch[i] = lo;
                }
            }
        }
    }

    // exact f64 re-rank of this thread's 20 survivors
    const double qxd = (double)qx, qyd = (double)qy, qzd = (double)qz;
    const double a2qd = qxd * qxd + qyd * qyd + qzd * qzd;
    unsigned long long kk[20];
#pragma unroll
    for (int i = 0; i < 20; ++i) {
        const int j = (int)(ch[i] & 0xFFFu);
        const float4 cc = P4[j];
        const double cx = (double)(-0.5f * cc.x);
        const double cy = (double)(-0.5f * cc.y);
        const double cz = (double)(-0.5f * cc.z);
        const double a2cd = cx * cx + cy * cy + cz * cz;
        const double ddot = qxd * cx + qyd * cy + qzd * cz;
        double dv = (a2qd + a2cd) - 2.0 * ddot;
        dv = (dv < 0.0) ? 0.0 : dv;
        if (j == n) dv = 0.0;
        union { double d; unsigned long long u; } cv; cv.d = dv;
        kk[i] = (cv.u & ~0xFFFULL) | (unsigned long long)j;
    }
    __syncthreads();   // everyone done reading P4 — safe to alias
#pragma unroll
    for (int i = 0; i < 20; ++i) kbuf[ql * 81 + s * 20 + i] = kk[i];
    __syncthreads();

    if (s == 0) {
        unsigned long long sel[Kv];
#pragma unroll
        for (int i = 0; i < Kv; ++i) sel[i] = ~0ull;
        for (int t = 0; t < 80; ++t) {
            const unsigned long long cand = kbuf[ql * 81 + t];
            if (cand < sel[Kv - 1]) {
                unsigned long long c = cand;
#pragma unroll
                for (int i = 0; i < Kv; ++i) {
                    const unsigned long long lo = (sel[i] < c) ? sel[i] : c;
                    const unsigned long long hi = (sel[i] < c) ? c : sel[i];
                    sel[i] = lo; c = hi;
                }
            }
        }
#pragma unroll
        for (int i = 0; i < Kv; ++i)
            idx_out[(long)q * Kv + i] = (int)(sel[i] & 0xFFFull);
    }
}

// ---------------- K3: gather + attention + RPE bias + output projection ----
__global__ __launch_bounds__(256) void attn_kernel(
    const unsigned short* __restrict__ qb, const unsigned short* __restrict__ kb,
    const unsigned short* __restrict__ vb, const int* __restrict__ idx,
    const float* __restrict__ pos, const float* __restrict__ W1,
    const float* __restrict__ b1, const float* __restrict__ w2sum,
    const float* __restrict__ b2sum, const float* __restrict__ Wp,
    const float* __restrict__ bp, float* __restrict__ out)
{
    __shared__ float q_lds[8][Cv];
    __shared__ float o_lds[8][Cv];
    __shared__ float lg[8][Kv];
    __shared__ float wgt[8][Kv];
    __shared__ int idx_l[8][Kv];
    __shared__ float W1l[3 * RPEv];
    __shared__ float b1l[RPEv], w2s[RPEv];
    __shared__ float posq[24];
    __shared__ float b2s_l;

    const int tid = threadIdx.x;
    const long r0 = (long)blockIdx.x * 8;   // 8 query rows per block
    const int bq = (int)(r0 >> 12);

    {
        float* ql = &q_lds[0][0];
        for (int i = tid; i < 8 * Cv; i += 256) ql[i] = bf2f(qb[r0 * Cv + i]);
    }
    if (tid < 128) ((int*)idx_l)[tid] = idx[r0 * Kv + tid];
    if (tid < 3 * RPEv) W1l[tid] = W1[tid];
    if (tid < RPEv) { b1l[tid] = b1[tid]; w2s[tid] = w2sum[tid]; }
    if (tid < 24) posq[tid] = pos[r0 * 3 + tid];
    if (tid == 0) b2s_l = *b2sum;
    __syncthreads();

    const int g = tid >> 4, l = tid & 15;   // 16 groups x 16 lanes
    for (int r = 0; r < 8; ++r) {
        const int nb = idx_l[r][g];
        const long gi = (long)bq * Nv + nb;
        const unsigned short* kr = kb + gi * Cv + l * 16;
        const float* qq = &q_lds[r][l * 16];
        const uint4 kA = *(const uint4*)kr;
        const uint4 kB = *(const uint4*)(kr + 8);
        float part = 0.f;
        part = fmaf(qq[0],  bf2f(kA.x & 0xffffu), part);
        part = fmaf(qq[1],  bf2f(kA.x >> 16),     part);
        part = fmaf(qq[2],  bf2f(kA.y & 0xffffu), part);
        part = fmaf(qq[3],  bf2f(kA.y >> 16),     part);
        part = fmaf(qq[4],  bf2f(kA.z & 0xffffu), part);
        part = fmaf(qq[5],  bf2f(kA.z >> 16),     part);
        part = fmaf(qq[6],  bf2f(kA.w & 0xffffu), part);
        part = fmaf(qq[7],  bf2f(kA.w >> 16),     part);
        part = fmaf(qq[8],  bf2f(kB.x & 0xffffu), part);
        part = fmaf(qq[9],  bf2f(kB.x >> 16),     part);
        part = fmaf(qq[10], bf2f(kB.y & 0xffffu), part);
        part = fmaf(qq[11], bf2f(kB.y >> 16),     part);
        part = fmaf(qq[12], bf2f(kB.z & 0xffffu), part);
        part = fmaf(qq[13], bf2f(kB.z >> 16),     part);
        part = fmaf(qq[14], bf2f(kB.w & 0xffffu), part);
        part = fmaf(qq[15], bf2f(kB.w >> 16),     part);
        // relative-position MLP, channel-summed: relu(rel@W1+b1) . w2sum
        const float rx = posq[r * 3 + 0] - pos[gi * 3 + 0];
        const float ry = posq[r * 3 + 1] - pos[gi * 3 + 1];
        const float rz = posq[r * 3 + 2] - pos[gi * 3 + 2];
#pragma unroll
        for (int u4 = 0; u4 < 4; ++u4) {
            const int u = l * 4 + u4;
            float h = fmaf(rx, W1l[u], fmaf(ry, W1l[RPEv + u], fmaf(rz, W1l[2 * RPEv + u], b1l[u])));
            h = fmaxf(h, 0.f);
            part = fmaf(h, w2s[u], part);
        }
        part += __shfl_xor(part, 8);
        part += __shfl_xor(part, 4);
        part += __shfl_xor(part, 2);
        part += __shfl_xor(part, 1);
        if (l == 0) lg[r][g] = (part + b2s_l) * 0.0625f;
    }
    __syncthreads();
    if (tid < 128) {
        const int rr = tid >> 4, gg = tid & 15;
        const float v = lg[rr][gg];
        float m = v;
        m = fmaxf(m, __shfl_xor(m, 8)); m = fmaxf(m, __shfl_xor(m, 4));
        m = fmaxf(m, __shfl_xor(m, 2)); m = fmaxf(m, __shfl_xor(m, 1));
        const float e = __expf(v - m);
        float ssum = e;
        ssum += __shfl_xor(ssum, 8); ssum += __shfl_xor(ssum, 4);
        ssum += __shfl_xor(ssum, 2); ssum += __shfl_xor(ssum, 1);
        wgt[rr][gg] = e / ssum;
    }
    __syncthreads();
    {
        const int c = tid;
        for (int r = 0; r < 8; ++r) {
            float acc = 0.f;
#pragma unroll
            for (int t = 0; t < Kv; ++t) {
                const long gi = (long)bq * Nv + idx_l[r][t];
                acc = fmaf(wgt[r][t], bf2f((unsigned)vb[gi * Cv + c]), acc);
            }
            o_lds[r][c] = acc;
        }
    }
    __syncthreads();
    {
        const int j = tid;
        float accf[8] = {0.f, 0.f, 0.f, 0.f, 0.f, 0.f, 0.f, 0.f};
        for (int c = 0; c < Cv; c += 4) {
            const float wp0 = Wp[(c + 0) * Cv + j];
            const float wp1 = Wp[(c + 1) * Cv + j];
            const float wp2 = Wp[(c + 2) * Cv + j];
            const float wp3 = Wp[(c + 3) * Cv + j];
#pragma unroll
            for (int r = 0; r < 8; ++r) {
                const float4 o4 = *(const float4*)&o_lds[r][c];
                accf[r] = fmaf(o4.x, wp0, fmaf(o4.y, wp1, fmaf(o4.z, wp2, fmaf(o4.w, wp3, accf[r]))));
            }
        }
        const float bpj = bp[j];
#pragma unroll
        for (int r = 0; r < 8; ++r)
            out[(r0 + r) * Cv + j] = accf[r] + bpj;
    }
}

extern "C" void kernel_launch(void* const* d_in, const int* in_sizes, int n_in,
                              void* d_out, int out_size, void* d_ws, size_t ws_size,
                              hipStream_t stream) {
    (void)in_sizes; (void)n_in; (void)out_size; (void)ws_size;
    const float* x      = (const float*)d_in[0];
    const float* pos    = (const float*)d_in[1];
    const float* Wq     = (const float*)d_in[2];
    const float* Wk     = (const float*)d_in[3];
    const float* Wv     = (const float*)d_in[4];
    const float* W1     = (const float*)d_in[5];
    const float* b1     = (const float*)d_in[6];
    const float* W2     = (const float*)d_in[7];
    const float* b2     = (const float*)d_in[8];
    const float* Wp     = (const float*)d_in[9];
    const float* bp     = (const float*)d_in[10];
    const float* gq     = (const float*)d_in[11];
    const float* betaq  = (const float*)d_in[12];
    const float* gkv    = (const float*)d_in[13];
    const float* betakv = (const float*)d_in[14];
    float* out = (float*)d_out;

    char* ws = (char*)d_ws;
    unsigned short* qb = (unsigned short*)(ws);               // 3 x 16 MiB bf16 q/k/v
    unsigned short* kb = (unsigned short*)(ws + 16777216);
    unsigned short* vb = (unsigned short*)(ws + 33554432);
    int*   idx   = (int*)  (ws + 50331648);                   // 2 MiB
    unsigned short* Bt = (unsigned short*)(ws + 52428800);    // 768*256*2 = 384 KiB
    float* w2sum = (float*)(ws + 52822016);                   // 64 floats
    float* b2sum = (float*)(ws + 52822272);                   // 1 float

    // d_out doubles as scratch for the bf16 LN outputs (dead until attn writes)
    unsigned short* Aq  = (unsigned short*)d_out;             // 16 MiB
    unsigned short* Akv = (unsigned short*)d_out + 8388608;   // 16 MiB

    hipLaunchKernelGGL(prep_kernel, dim3(1), dim3(64), 0, stream, W2, b2, w2sum, b2sum);
    hipLaunchKernelGGL(wcast_kernel, dim3(768), dim3(256), 0, stream, Wq, Wk, Wv, Bt);
    hipLaunchKernelGGL(ln_cast_kernel, dim3(4096), dim3(256), 0, stream,
                       x, gq, betaq, gkv, betakv, Aq, Akv);
    hipLaunchKernelGGL(gemm_qkv_kernel, dim3(256, 6), dim3(256), 0, stream,
                       Aq, Akv, Bt, qb, kb, vb);
    hipLaunchKernelGGL(knn_kernel, dim3(512), dim3(256), 0, stream, pos, idx);
    hipLaunchKernelGGL(attn_kernel, dim3(4096), dim3(256), 0, stream,
                       qb, kb, vb, idx, pos, W1, b1, w2sum, b2sum, Wp, bp, out);
}

// Round 4
// 355.744 us; speedup vs baseline: 4.0517x; 1.1733x over previous
//
#include <hip/hip_runtime.h>
#include <hip/hip_bf16.h>
#include <stdint.h>

#define Bv 8
#define Nv 4096
#define Cv 256
#define Kv 16
#define RPEv 64
#define CAPv 128

typedef short bf16x8 __attribute__((ext_vector_type(8)));
typedef float f32x4 __attribute__((ext_vector_type(4)));

static __device__ __forceinline__ float bf2f(unsigned int u16) {
    union { unsigned int i; float f; } v; v.i = u16 << 16; return v.f;
}
static __device__ __forceinline__ unsigned short f2bf(float f) {
    union { float f; unsigned int i; } v; v.f = f;
    unsigned int x = v.i;
    return (unsigned short)((x + 0x7fffu + ((x >> 16) & 1u)) >> 16);
}
static __device__ __forceinline__ unsigned int umin32(unsigned int a, unsigned int b) { return a < b ? a : b; }
static __device__ __forceinline__ unsigned int umax32(unsigned int a, unsigned int b) { return a > b ? a : b; }
static __device__ __forceinline__ float f16lo(unsigned int u) {
    _Float16 h = __builtin_bit_cast(_Float16, (unsigned short)(u & 0xffffu)); return (float)h;
}
static __device__ __forceinline__ float f16hi(unsigned int u) {
    _Float16 h = __builtin_bit_cast(_Float16, (unsigned short)(u >> 16)); return (float)h;
}
static __device__ __forceinline__ unsigned short f2h(float f) {
    _Float16 h = (_Float16)f; return __builtin_bit_cast(unsigned short, h);
}

// ---------------- K0: tiny prep (w2sum = colsum over C of W2, b2sum) -------
__global__ void prep_kernel(const float* __restrict__ W2, const float* __restrict__ b2,
                            float* __restrict__ w2sum, float* __restrict__ b2sum) {
    const int u = threadIdx.x;
    if (u < RPEv) {
        float s = 0.f;
        for (int c = 0; c < Cv; ++c) s += W2[u * Cv + c];
        w2sum[u] = s;
    }
    if (u == 0) {
        float s = 0.f;
        for (int c = 0; c < Cv; ++c) s += b2[c];
        *b2sum = s;
    }
}

// ---------------- K0b: weight transpose-cast -> Bt[768][256] bf16 ----------
__global__ __launch_bounds__(256) void wcast_kernel(
    const float* __restrict__ Wq, const float* __restrict__ Wk,
    const float* __restrict__ Wv, unsigned short* __restrict__ Bt)
{
    const int r = blockIdx.x;       // 0..767
    const int t = threadIdx.x;      // k
    const float* W = (r < 256) ? Wq : (r < 512) ? Wk : Wv;
    const int n = r & 255;
    Bt[r * 256 + t] = f2bf(W[t * 256 + n]);
}

// ---------------- K1a: dual LayerNorm + bf16 cast (A matrices) -------------
__global__ __launch_bounds__(256) void ln_cast_kernel(
    const float* __restrict__ x,
    const float* __restrict__ gq, const float* __restrict__ bq,
    const float* __restrict__ gkv, const float* __restrict__ bkv,
    unsigned short* __restrict__ Aq, unsigned short* __restrict__ Akv)
{
    const int tid = threadIdx.x;
    const long r0 = (long)blockIdx.x * 8;
    const int row = tid >> 5;          // 32 threads per row
    const int c0 = (tid & 31) * 8;     // 8 consecutive channels each
    const float* xr = x + (r0 + row) * Cv + c0;
    float xv[8];
    *(float4*)&xv[0] = *(const float4*)xr;
    *(float4*)&xv[4] = *(const float4*)(xr + 4);
    float s = 0.f, s2 = 0.f;
#pragma unroll
    for (int i = 0; i < 8; ++i) { s += xv[i]; s2 = fmaf(xv[i], xv[i], s2); }
#pragma unroll
    for (int m = 16; m >= 1; m >>= 1) { s += __shfl_xor(s, m); s2 += __shfl_xor(s2, m); }
    const float mean = s * (1.f / Cv);
    const float var = fmaf(-mean, mean, s2 * (1.f / Cv));
    const float rs = rsqrtf(fmaxf(var, 0.f) + 1e-5f);
    unsigned int pq[4], pk[4];
#pragma unroll
    for (int i = 0; i < 4; ++i) {
        const int c = c0 + 2 * i;
        const float h0 = (xv[2 * i] - mean) * rs;
        const float h1 = (xv[2 * i + 1] - mean) * rs;
        const unsigned int q0 = f2bf(fmaf(h0, gq[c], bq[c]));
        const unsigned int q1 = f2bf(fmaf(h1, gq[c + 1], bq[c + 1]));
        const unsigned int k0 = f2bf(fmaf(h0, gkv[c], bkv[c]));
        const unsigned int k1 = f2bf(fmaf(h1, gkv[c + 1], bkv[c + 1]));
        pq[i] = q0 | (q1 << 16);
        pk[i] = k0 | (k1 << 16);
    }
    const long off = (r0 + row) * Cv + c0;
    *(uint4*)&Aq[off]  = make_uint4(pq[0], pq[1], pq[2], pq[3]);
    *(uint4*)&Akv[off] = make_uint4(pk[0], pk[1], pk[2], pk[3]);
}

// ---------------- K1b: bf16 MFMA GEMM  C[32768 x 768] = A @ W --------------
__global__ __launch_bounds__(256) void gemm_qkv_kernel(
    const unsigned short* __restrict__ Aq, const unsigned short* __restrict__ Akv,
    const unsigned short* __restrict__ Bt,
    unsigned short* __restrict__ qo, unsigned short* __restrict__ ko,
    unsigned short* __restrict__ vo)
{
    __shared__ unsigned short Albs[2][128 * 64];
    __shared__ unsigned short Blbs[2][128 * 64];

    const int tid = threadIdx.x;
    const int rt = blockIdx.x;          // row tile: 256
    const int ct = blockIdx.y;          // col tile: 6
    const unsigned short* A = (ct < 2) ? Aq : Akv;
    const int mat = ct >> 1;
    unsigned short* outp = (mat == 0) ? qo : (mat == 1) ? ko : vo;
    const int colInMat = (ct & 1) * 128;

    const int wid = tid >> 6, l = tid & 63;
    const int wr = wid >> 1, wc = wid & 1;

    int srow[4], scol8[4];
#pragma unroll
    for (int it = 0; it < 4; ++it) {
        const int chunk = it * 256 + tid;
        srow[it] = chunk >> 3;
        scol8[it] = ((chunk & 7) ^ (srow[it] & 7)) * 8;
    }

#define STAGE(buf, ks)                                                                  \
    {                                                                                   \
        _Pragma("unroll")                                                               \
        for (int it = 0; it < 4; ++it) {                                                \
            const unsigned short* ga = A + ((size_t)(rt * 128 + srow[it])) * 256        \
                                         + (ks) * 64 + scol8[it];                       \
            const unsigned short* gb = Bt + ((size_t)(ct * 128 + srow[it])) * 256       \
                                          + (ks) * 64 + scol8[it];                      \
            __builtin_amdgcn_global_load_lds(                                           \
                (const __attribute__((address_space(1))) unsigned int*)(const void*)ga, \
                (__attribute__((address_space(3))) unsigned int*)(void*)                \
                    ((char*)&Albs[buf][0] + (it * 256 + tid) * 16), 16, 0, 0);          \
            __builtin_amdgcn_global_load_lds(                                           \
                (const __attribute__((address_space(1))) unsigned int*)(const void*)gb, \
                (__attribute__((address_space(3))) unsigned int*)(void*)                \
                    ((char*)&Blbs[buf][0] + (it * 256 + tid) * 16), 16, 0, 0);          \
        }                                                                               \
    }

    f32x4 acc[4][4];
#pragma unroll
    for (int m = 0; m < 4; ++m)
#pragma unroll
        for (int n = 0; n < 4; ++n) acc[m][n] = (f32x4){0.f, 0.f, 0.f, 0.f};

    STAGE(0, 0);
    __syncthreads();

    for (int ks = 0; ks < 4; ++ks) {
        const int cur = ks & 1;
        if (ks < 3) STAGE(cur ^ 1, ks + 1);
#pragma unroll
        for (int kk = 0; kk < 2; ++kk) {
            bf16x8 a[4], b[4];
#pragma unroll
            for (int m = 0; m < 4; ++m) {
                const int row = wr * 64 + m * 16 + (l & 15);
                const int byte = row * 128 + ((((kk * 4 + (l >> 4)) * 16)) ^ ((row & 7) << 4));
                a[m] = *(const bf16x8*)((const char*)&Albs[cur][0] + byte);
            }
#pragma unroll
            for (int n = 0; n < 4; ++n) {
                const int row = wc * 64 + n * 16 + (l & 15);
                const int byte = row * 128 + ((((kk * 4 + (l >> 4)) * 16)) ^ ((row & 7) << 4));
                b[n] = *(const bf16x8*)((const char*)&Blbs[cur][0] + byte);
            }
#pragma unroll
            for (int m = 0; m < 4; ++m)
#pragma unroll
                for (int n = 0; n < 4; ++n)
                    acc[m][n] = __builtin_amdgcn_mfma_f32_16x16x32_bf16(a[m], b[n], acc[m][n], 0, 0, 0);
        }
        __syncthreads();
    }

#pragma unroll
    for (int m = 0; m < 4; ++m) {
#pragma unroll
        for (int n = 0; n < 4; ++n) {
#pragma unroll
            for (int j = 0; j < 4; ++j) {
                const int row = rt * 128 + wr * 64 + m * 16 + (l >> 4) * 4 + j;
                const int col = colInMat + wc * 64 + n * 16 + (l & 15);
                outp[(size_t)row * 256 + col] = f2bf(acc[m][n][j]);
            }
        }
    }
#undef STAGE
}

// ---------------- K2: kNN v3 — fp16 filter + exact f64 select --------------
// Pass A: 4 thr/query chain-4 on fp16 distances -> tau (>= true d16, x1.10).
// Pass B: flipped layout, 16 reg-candidates/thread vs 64 queries, LDS append.
// Tail: 1 thr/query exact f64 re-rank of survivors (bit-identical comparator).
__global__ __launch_bounds__(256) void knn_kernel(
    const float* __restrict__ pos, int* __restrict__ idx_out)
{
    __shared__ uint2 P2[Nv];                 // 32 KiB fp16-packed (x,y | z,-)
    __shared__ float4 qf[64];                // qx,qy,qz,tauInf
    __shared__ unsigned int ttmp[256];
    __shared__ unsigned int cnt[64];
    __shared__ unsigned short bufs[64 * CAPv];   // 16 KiB survivor indices

    const int tid = threadIdx.x;
    const int ql = tid >> 2;                 // query within block
    const int s  = tid & 3;                  // segment
    const int q  = blockIdx.x * 64 + ql;
    const int b  = q >> 12;
    const int n  = q & (Nv - 1);
    const float* pb = pos + (size_t)b * Nv * 3;

    for (int i = tid; i < Nv; i += 256) {
        const float px = pb[3 * i], py = pb[3 * i + 1], pz = pb[3 * i + 2];
        P2[i] = make_uint2((unsigned int)f2h(px) | ((unsigned int)f2h(py) << 16),
                           (unsigned int)f2h(pz));
    }
    __syncthreads();

    // ---- Pass A: chain-4 of f32 bit-patterns of fp16-derived distances ----
    const uint2 selfp = P2[n];
    const float qx = f16lo(selfp.x), qy = f16hi(selfp.x), qz = f16lo(selfp.y);

    unsigned int ch[4] = {0xFFFFFFFFu, 0xFFFFFFFFu, 0xFFFFFFFFu, 0xFFFFFFFFu};
    const uint4* P4v = (const uint4*)P2;
    for (int t = 0; t < 512; ++t) {
        const uint4 cc = P4v[4 * t + s];     // candidates j0=2p, j1=2p+1
        const float dx0 = f16lo(cc.x) - qx, dy0 = f16hi(cc.x) - qy, dz0 = f16lo(cc.y) - qz;
        const float dx1 = f16lo(cc.z) - qx, dy1 = f16hi(cc.z) - qy, dz1 = f16lo(cc.w) - qz;
        const float d0 = fmaf(dx0, dx0, fmaf(dy0, dy0, dz0 * dz0));
        const float d1 = fmaf(dx1, dx1, fmaf(dy1, dy1, dz1 * dz1));
        const unsigned int k0 = __float_as_uint(d0);
        const unsigned int k1 = __float_as_uint(d1);
        const unsigned int klo = umin32(k0, k1);
        const unsigned int khi = umax32(k0, k1);
        if (klo < ch[3]) {
            unsigned int c = klo;
#pragma unroll
            for (int i = 0; i < 4; ++i) {
                const unsigned int lo = umin32(ch[i], c);
                c = umax32(ch[i], c);
                ch[i] = lo;
            }
            if (khi < ch[3]) {
                unsigned int c2 = khi;
#pragma unroll
                for (int i = 0; i < 4; ++i) {
                    const unsigned int lo = umin32(ch[i], c2);
                    c2 = umax32(ch[i], c2);
                    ch[i] = lo;
                }
            }
        }
    }
    ttmp[tid] = ch[3];
    __syncthreads();

    if (tid < 64) {
        const unsigned int tu = umax32(umax32(ttmp[4 * tid], ttmp[4 * tid + 1]),
                                       umax32(ttmp[4 * tid + 2], ttmp[4 * tid + 3]));
        const float tauInf = __uint_as_float(tu) * 1.10f + 1e-20f;
        const int n2 = (blockIdx.x * 64 + tid) & (Nv - 1);
        const uint2 qp = P2[n2];
        qf[tid] = make_float4(f16lo(qp.x), f16hi(qp.x), f16lo(qp.y), tauInf);
        cnt[tid] = 0;
    }
    __syncthreads();

    // ---- Pass B: 16 register candidates vs 64 queries ----
    float cx[16], cy[16], cz[16];
#pragma unroll
    for (int k = 0; k < 16; ++k) {
        const uint2 u = P2[tid + (k << 8)];
        cx[k] = f16lo(u.x); cy[k] = f16hi(u.x); cz[k] = f16lo(u.y);
    }
    for (int q2 = 0; q2 < 64; ++q2) {
        const float4 Q = qf[q2];
#pragma unroll
        for (int k = 0; k < 16; ++k) {
            const float dx = cx[k] - Q.x, dy = cy[k] - Q.y, dz = cz[k] - Q.z;
            const float d2 = fmaf(dx, dx, fmaf(dy, dy, dz * dz));
            if (d2 < Q.w) {
                const unsigned int slot = atomicAdd(&cnt[q2], 1u);
                if (slot < CAPv) bufs[q2 * CAPv + slot] = (unsigned short)(tid + (k << 8));
            }
        }
    }
    __syncthreads();

    // ---- Tail: exact f64 re-rank (identical comparator to prior rounds) ---
    if (tid < 64) {
        const int q2 = blockIdx.x * 64 + tid;
        const int n2 = q2 & (Nv - 1);
        const int b2 = q2 >> 12;
        const float* pb2 = pos + (size_t)b2 * Nv * 3;
        const double qxd = (double)pb2[3 * n2];
        const double qyd = (double)pb2[3 * n2 + 1];
        const double qzd = (double)pb2[3 * n2 + 2];
        const double a2qd = qxd * qxd + qyd * qyd + qzd * qzd;
        int c = (int)cnt[tid]; if (c > CAPv) c = CAPv;
        unsigned long long sel[Kv];
#pragma unroll
        for (int i = 0; i < Kv; ++i) sel[i] = ~0ull;
        for (int t = 0; t < c; ++t) {
            const int j = bufs[tid * CAPv + t];
            const double cxd = (double)pb2[3 * j];
            const double cyd = (double)pb2[3 * j + 1];
            const double czd = (double)pb2[3 * j + 2];
            const double a2cd = cxd * cxd + cyd * cyd + czd * czd;
            const double ddot = qxd * cxd + qyd * cyd + qzd * czd;
            double dv = (a2qd + a2cd) - 2.0 * ddot;
            dv = (dv < 0.0) ? 0.0 : dv;
            if (j == n2) dv = 0.0;
            union { double d; unsigned long long u; } cv; cv.d = dv;
            const unsigned long long key = (cv.u & ~0xFFFULL) | (unsigned long long)j;
            if (key < sel[Kv - 1]) {
                unsigned long long cc = key;
#pragma unroll
                for (int i = 0; i < Kv; ++i) {
                    const unsigned long long lo = (sel[i] < cc) ? sel[i] : cc;
                    const unsigned long long hi = (sel[i] < cc) ? cc : sel[i];
                    sel[i] = lo; cc = hi;
                }
            }
        }
#pragma unroll
        for (int i = 0; i < Kv; ++i)
            idx_out[(long)q2 * Kv + i] = (int)(sel[i] & 0xFFFull);
    }
}

// ---------------- K3: gather + attention + RPE bias + output projection ----
__global__ __launch_bounds__(256) void attn_kernel(
    const unsigned short* __restrict__ qb, const unsigned short* __restrict__ kb,
    const unsigned short* __restrict__ vb, const int* __restrict__ idx,
    const float* __restrict__ pos, const float* __restrict__ W1,
    const float* __restrict__ b1, const float* __restrict__ w2sum,
    const float* __restrict__ b2sum, const float* __restrict__ Wp,
    const float* __restrict__ bp, float* __restrict__ out)
{
    __shared__ float q_lds[8][Cv];
    __shared__ float o_lds[8][Cv];
    __shared__ float lg[8][Kv];
    __shared__ float wgt[8][Kv];
    __shared__ int idx_l[8][Kv];
    __shared__ float W1l[3 * RPEv];
    __shared__ float b1l[RPEv], w2s[RPEv];
    __shared__ float posq[24];
    __shared__ float b2s_l;

    const int tid = threadIdx.x;
    const long r0 = (long)blockIdx.x * 8;   // 8 query rows per block
    const int bq = (int)(r0 >> 12);

    {
        float* ql = &q_lds[0][0];
        for (int i = tid; i < 8 * Cv; i += 256) ql[i] = bf2f(qb[r0 * Cv + i]);
    }
    if (tid < 128) ((int*)idx_l)[tid] = idx[r0 * Kv + tid];
    if (tid < 3 * RPEv) W1l[tid] = W1[tid];
    if (tid < RPEv) { b1l[tid] = b1[tid]; w2s[tid] = w2sum[tid]; }
    if (tid < 24) posq[tid] = pos[r0 * 3 + tid];
    if (tid == 0) b2s_l = *b2sum;
    __syncthreads();

    const int g = tid >> 4, l = tid & 15;   // 16 groups x 16 lanes
    for (int r = 0; r < 8; ++r) {
        const int nb = idx_l[r][g];
        const long gi = (long)bq * Nv + nb;
        const unsigned short* kr = kb + gi * Cv + l * 16;
        const float* qq = &q_lds[r][l * 16];
        const uint4 kA = *(const uint4*)kr;
        const uint4 kB = *(const uint4*)(kr + 8);
        float part = 0.f;
        part = fmaf(qq[0],  bf2f(kA.x & 0xffffu), part);
        part = fmaf(qq[1],  bf2f(kA.x >> 16),     part);
        part = fmaf(qq[2],  bf2f(kA.y & 0xffffu), part);
        part = fmaf(qq[3],  bf2f(kA.y >> 16),     part);
        part = fmaf(qq[4],  bf2f(kA.z & 0xffffu), part);
        part = fmaf(qq[5],  bf2f(kA.z >> 16),     part);
        part = fmaf(qq[6],  bf2f(kA.w & 0xffffu), part);
        part = fmaf(qq[7],  bf2f(kA.w >> 16),     part);
        part = fmaf(qq[8],  bf2f(kB.x & 0xffffu), part);
        part = fmaf(qq[9],  bf2f(kB.x >> 16),     part);
        part = fmaf(qq[10], bf2f(kB.y & 0xffffu), part);
        part = fmaf(qq[11], bf2f(kB.y >> 16),     part);
        part = fmaf(qq[12], bf2f(kB.z & 0xffffu), part);
        part = fmaf(qq[13], bf2f(kB.z >> 16),     part);
        part = fmaf(qq[14], bf2f(kB.w & 0xffffu), part);
        part = fmaf(qq[15], bf2f(kB.w >> 16),     part);
        const float rx = posq[r * 3 + 0] - pos[gi * 3 + 0];
        const float ry = posq[r * 3 + 1] - pos[gi * 3 + 1];
        const float rz = posq[r * 3 + 2] - pos[gi * 3 + 2];
#pragma unroll
        for (int u4 = 0; u4 < 4; ++u4) {
            const int u = l * 4 + u4;
            float h = fmaf(rx, W1l[u], fmaf(ry, W1l[RPEv + u], fmaf(rz, W1l[2 * RPEv + u], b1l[u])));
            h = fmaxf(h, 0.f);
            part = fmaf(h, w2s[u], part);
        }
        part += __shfl_xor(part, 8);
        part += __shfl_xor(part, 4);
        part += __shfl_xor(part, 2);
        part += __shfl_xor(part, 1);
        if (l == 0) lg[r][g] = (part + b2s_l) * 0.0625f;
    }
    __syncthreads();
    if (tid < 128) {
        const int rr = tid >> 4, gg = tid & 15;
        const float v = lg[rr][gg];
        float m = v;
        m = fmaxf(m, __shfl_xor(m, 8)); m = fmaxf(m, __shfl_xor(m, 4));
        m = fmaxf(m, __shfl_xor(m, 2)); m = fmaxf(m, __shfl_xor(m, 1));
        const float e = __expf(v - m);
        float ssum = e;
        ssum += __shfl_xor(ssum, 8); ssum += __shfl_xor(ssum, 4);
        ssum += __shfl_xor(ssum, 2); ssum += __shfl_xor(ssum, 1);
        wgt[rr][gg] = e / ssum;
    }
    __syncthreads();
    {
        const int c = tid;
        for (int r = 0; r < 8; ++r) {
            float acc = 0.f;
#pragma unroll
            for (int t = 0; t < Kv; ++t) {
                const long gi = (long)bq * Nv + idx_l[r][t];
                acc = fmaf(wgt[r][t], bf2f((unsigned)vb[gi * Cv + c]), acc);
            }
            o_lds[r][c] = acc;
        }
    }
    __syncthreads();
    {
        const int j = tid;
        float accf[8] = {0.f, 0.f, 0.f, 0.f, 0.f, 0.f, 0.f, 0.f};
        for (int c = 0; c < Cv; c += 4) {
            const float wp0 = Wp[(c + 0) * Cv + j];
            const float wp1 = Wp[(c + 1) * Cv + j];
            const float wp2 = Wp[(c + 2) * Cv + j];
            const float wp3 = Wp[(c + 3) * Cv + j];
#pragma unroll
            for (int r = 0; r < 8; ++r) {
                const float4 o4 = *(const float4*)&o_lds[r][c];
                accf[r] = fmaf(o4.x, wp0, fmaf(o4.y, wp1, fmaf(o4.z, wp2, fmaf(o4.w, wp3, accf[r]))));
            }
        }
        const float bpj = bp[j];
#pragma unroll
        for (int r = 0; r < 8; ++r)
            out[(r0 + r) * Cv + j] = accf[r] + bpj;
    }
}

extern "C" void kernel_launch(void* const* d_in, const int* in_sizes, int n_in,
                              void* d_out, int out_size, void* d_ws, size_t ws_size,
                              hipStream_t stream) {
    (void)in_sizes; (void)n_in; (void)out_size; (void)ws_size;
    const float* x      = (const float*)d_in[0];
    const float* pos    = (const float*)d_in[1];
    const float* Wq     = (const float*)d_in[2];
    const float* Wk     = (const float*)d_in[3];
    const float* Wv     = (const float*)d_in[4];
    const float* W1     = (const float*)d_in[5];
    const float* b1     = (const float*)d_in[6];
    const float* W2     = (const float*)d_in[7];
    const float* b2     = (const float*)d_in[8];
    const float* Wp     = (const float*)d_in[9];
    const float* bp     = (const float*)d_in[10];
    const float* gq     = (const float*)d_in[11];
    const float* betaq  = (const float*)d_in[12];
    const float* gkv    = (const float*)d_in[13];
    const float* betakv = (const float*)d_in[14];
    float* out = (float*)d_out;

    char* ws = (char*)d_ws;
    unsigned short* qb = (unsigned short*)(ws);               // 3 x 16 MiB bf16 q/k/v
    unsigned short* kb = (unsigned short*)(ws + 16777216);
    unsigned short* vb = (unsigned short*)(ws + 33554432);
    int*   idx   = (int*)  (ws + 50331648);                   // 2 MiB
    unsigned short* Bt = (unsigned short*)(ws + 52428800);    // 384 KiB
    float* w2sum = (float*)(ws + 52822016);
    float* b2sum = (float*)(ws + 52822272);

    unsigned short* Aq  = (unsigned short*)d_out;             // d_out as scratch
    unsigned short* Akv = (unsigned short*)d_out + 8388608;

    hipLaunchKernelGGL(prep_kernel, dim3(1), dim3(64), 0, stream, W2, b2, w2sum, b2sum);
    hipLaunchKernelGGL(wcast_kernel, dim3(768), dim3(256), 0, stream, Wq, Wk, Wv, Bt);
    hipLaunchKernelGGL(ln_cast_kernel, dim3(4096), dim3(256), 0, stream,
                       x, gq, betaq, gkv, betakv, Aq, Akv);
    hipLaunchKernelGGL(gemm_qkv_kernel, dim3(256, 6), dim3(256), 0, stream,
                       Aq, Akv, Bt, qb, kb, vb);
    hipLaunchKernelGGL(knn_kernel, dim3(512), dim3(256), 0, stream, pos, idx);
    hipLaunchKernelGGL(attn_kernel, dim3(4096), dim3(256), 0, stream,
                       qb, kb, vb, idx, pos, W1, b1, w2sum, b2sum, Wp, bp, out);
}

// Round 6
// 238.404 us; speedup vs baseline: 6.0459x; 1.4922x over previous
//
#include <hip/hip_runtime.h>
#include <hip/hip_bf16.h>
#include <stdint.h>

#define Bv 8
#define Nv 4096
#define Cv 256
#define Kv 16
#define RPEv 64
#define CAPv 160

typedef short bf16x8 __attribute__((ext_vector_type(8)));
typedef float f32x4 __attribute__((ext_vector_type(4)));

static __device__ __forceinline__ float bf2f(unsigned int u16) {
    union { unsigned int i; float f; } v; v.i = u16 << 16; return v.f;
}
static __device__ __forceinline__ unsigned short f2bf(float f) {
    union { float f; unsigned int i; } v; v.f = f;
    unsigned int x = v.i;
    return (unsigned short)((x + 0x7fffu + ((x >> 16) & 1u)) >> 16);
}
static __device__ __forceinline__ unsigned int umin32(unsigned int a, unsigned int b) { return a < b ? a : b; }
static __device__ __forceinline__ unsigned int umax32(unsigned int a, unsigned int b) { return a > b ? a : b; }
static __device__ __forceinline__ float f16lo(unsigned int u) {
    _Float16 h = __builtin_bit_cast(_Float16, (unsigned short)(u & 0xffffu)); return (float)h;
}
static __device__ __forceinline__ float f16hi(unsigned int u) {
    _Float16 h = __builtin_bit_cast(_Float16, (unsigned short)(u >> 16)); return (float)h;
}
static __device__ __forceinline__ unsigned short f2h(float f) {
    _Float16 h = (_Float16)f; return __builtin_bit_cast(unsigned short, h);
}

// ---------------- K0: tiny prep (w2sum = colsum over C of W2, b2sum) -------
__global__ void prep_kernel(const float* __restrict__ W2, const float* __restrict__ b2,
                            float* __restrict__ w2sum, float* __restrict__ b2sum) {
    const int u = threadIdx.x;
    if (u < RPEv) {
        float s = 0.f;
        for (int c = 0; c < Cv; ++c) s += W2[u * Cv + c];
        w2sum[u] = s;
    }
    if (u == 0) {
        float s = 0.f;
        for (int c = 0; c < Cv; ++c) s += b2[c];
        *b2sum = s;
    }
}

// ---------------- K0b: weight transpose-cast -> Bt[1024][256] bf16 ---------
// rows 0-255: Wq^T, 256-511: Wk^T, 512-767: Wv^T, 768-1023: Wp^T
__global__ __launch_bounds__(256) void wcast_kernel(
    const float* __restrict__ Wq, const float* __restrict__ Wk,
    const float* __restrict__ Wv, const float* __restrict__ Wp,
    unsigned short* __restrict__ Bt)
{
    const int r = blockIdx.x;       // 0..1023
    const int t = threadIdx.x;      // k
    const float* W = (r < 256) ? Wq : (r < 512) ? Wk : (r < 768) ? Wv : Wp;
    const int n = r & 255;
    Bt[r * 256 + t] = f2bf(W[t * 256 + n]);
}

// ---------------- K1a: dual LayerNorm + bf16 cast (A matrices) -------------
__global__ __launch_bounds__(256) void ln_cast_kernel(
    const float* __restrict__ x,
    const float* __restrict__ gq, const float* __restrict__ bq,
    const float* __restrict__ gkv, const float* __restrict__ bkv,
    unsigned short* __restrict__ Aq, unsigned short* __restrict__ Akv)
{
    const int tid = threadIdx.x;
    const long r0 = (long)blockIdx.x * 8;
    const int row = tid >> 5;          // 32 threads per row
    const int c0 = (tid & 31) * 8;     // 8 consecutive channels each
    const float* xr = x + (r0 + row) * Cv + c0;
    float xv[8];
    *(float4*)&xv[0] = *(const float4*)xr;
    *(float4*)&xv[4] = *(const float4*)(xr + 4);
    float s = 0.f, s2 = 0.f;
#pragma unroll
    for (int i = 0; i < 8; ++i) { s += xv[i]; s2 = fmaf(xv[i], xv[i], s2); }
#pragma unroll
    for (int m = 16; m >= 1; m >>= 1) { s += __shfl_xor(s, m); s2 += __shfl_xor(s2, m); }
    const float mean = s * (1.f / Cv);
    const float var = fmaf(-mean, mean, s2 * (1.f / Cv));
    const float rs = rsqrtf(fmaxf(var, 0.f) + 1e-5f);
    unsigned int pq[4], pk[4];
#pragma unroll
    for (int i = 0; i < 4; ++i) {
        const int c = c0 + 2 * i;
        const float h0 = (xv[2 * i] - mean) * rs;
        const float h1 = (xv[2 * i + 1] - mean) * rs;
        const unsigned int q0 = f2bf(fmaf(h0, gq[c], bq[c]));
        const unsigned int q1 = f2bf(fmaf(h1, gq[c + 1], bq[c + 1]));
        const unsigned int k0 = f2bf(fmaf(h0, gkv[c], bkv[c]));
        const unsigned int k1 = f2bf(fmaf(h1, gkv[c + 1], bkv[c + 1]));
        pq[i] = q0 | (q1 << 16);
        pk[i] = k0 | (k1 << 16);
    }
    const long off = (r0 + row) * Cv + c0;
    *(uint4*)&Aq[off]  = make_uint4(pq[0], pq[1], pq[2], pq[3]);
    *(uint4*)&Akv[off] = make_uint4(pk[0], pk[1], pk[2], pk[3]);
}

// ---------------- K1b: bf16 MFMA GEMM  C[32768 x 768] = A @ W (bf16 out) ---
__global__ __launch_bounds__(256) void gemm_qkv_kernel(
    const unsigned short* __restrict__ Aq, const unsigned short* __restrict__ Akv,
    const unsigned short* __restrict__ Bt,
    unsigned short* __restrict__ qo, unsigned short* __restrict__ ko,
    unsigned short* __restrict__ vo)
{
    __shared__ unsigned short Albs[2][128 * 64];
    __shared__ unsigned short Blbs[2][128 * 64];

    const int tid = threadIdx.x;
    const int rt = blockIdx.x;          // row tile: 256
    const int ct = blockIdx.y;          // col tile: 6
    const unsigned short* A = (ct < 2) ? Aq : Akv;
    const int mat = ct >> 1;
    unsigned short* outp = (mat == 0) ? qo : (mat == 1) ? ko : vo;
    const int colInMat = (ct & 1) * 128;

    const int wid = tid >> 6, l = tid & 63;
    const int wr = wid >> 1, wc = wid & 1;

    int srow[4], scol8[4];
#pragma unroll
    for (int it = 0; it < 4; ++it) {
        const int chunk = it * 256 + tid;
        srow[it] = chunk >> 3;
        scol8[it] = ((chunk & 7) ^ (srow[it] & 7)) * 8;
    }

#define STAGE(buf, ks)                                                                  \
    {                                                                                   \
        _Pragma("unroll")                                                               \
        for (int it = 0; it < 4; ++it) {                                                \
            const unsigned short* ga = A + ((size_t)(rt * 128 + srow[it])) * 256        \
                                         + (ks) * 64 + scol8[it];                       \
            const unsigned short* gb = Bt + ((size_t)(ct * 128 + srow[it])) * 256       \
                                          + (ks) * 64 + scol8[it];                      \
            __builtin_amdgcn_global_load_lds(                                           \
                (const __attribute__((address_space(1))) unsigned int*)(const void*)ga, \
                (__attribute__((address_space(3))) unsigned int*)(void*)                \
                    ((char*)&Albs[buf][0] + (it * 256 + tid) * 16), 16, 0, 0);          \
            __builtin_amdgcn_global_load_lds(                                           \
                (const __attribute__((address_space(1))) unsigned int*)(const void*)gb, \
                (__attribute__((address_space(3))) unsigned int*)(void*)                \
                    ((char*)&Blbs[buf][0] + (it * 256 + tid) * 16), 16, 0, 0);          \
        }                                                                               \
    }

    f32x4 acc[4][4];
#pragma unroll
    for (int m = 0; m < 4; ++m)
#pragma unroll
        for (int n = 0; n < 4; ++n) acc[m][n] = (f32x4){0.f, 0.f, 0.f, 0.f};

    STAGE(0, 0);
    __syncthreads();

    for (int ks = 0; ks < 4; ++ks) {
        const int cur = ks & 1;
        if (ks < 3) STAGE(cur ^ 1, ks + 1);
#pragma unroll
        for (int kk = 0; kk < 2; ++kk) {
            bf16x8 a[4], b[4];
#pragma unroll
            for (int m = 0; m < 4; ++m) {
                const int row = wr * 64 + m * 16 + (l & 15);
                const int byte = row * 128 + ((((kk * 4 + (l >> 4)) * 16)) ^ ((row & 7) << 4));
                a[m] = *(const bf16x8*)((const char*)&Albs[cur][0] + byte);
            }
#pragma unroll
            for (int n = 0; n < 4; ++n) {
                const int row = wc * 64 + n * 16 + (l & 15);
                const int byte = row * 128 + ((((kk * 4 + (l >> 4)) * 16)) ^ ((row & 7) << 4));
                b[n] = *(const bf16x8*)((const char*)&Blbs[cur][0] + byte);
            }
#pragma unroll
            for (int m = 0; m < 4; ++m)
#pragma unroll
                for (int n = 0; n < 4; ++n)
                    acc[m][n] = __builtin_amdgcn_mfma_f32_16x16x32_bf16(a[m], b[n], acc[m][n], 0, 0, 0);
        }
        __syncthreads();
    }

#pragma unroll
    for (int m = 0; m < 4; ++m) {
#pragma unroll
        for (int n = 0; n < 4; ++n) {
#pragma unroll
            for (int j = 0; j < 4; ++j) {
                const int row = rt * 128 + wr * 64 + m * 16 + (l >> 4) * 4 + j;
                const int col = colInMat + wc * 64 + n * 16 + (l & 15);
                outp[(size_t)row * 256 + col] = f2bf(acc[m][n][j]);
            }
        }
    }
#undef STAGE
}

// ---------------- K4: proj GEMM  out[32768 x 256] = o @ Wp^T + bp (f32) ----
__global__ __launch_bounds__(256) void gemm_proj_kernel(
    const unsigned short* __restrict__ Ab, const unsigned short* __restrict__ Btp,
    const float* __restrict__ bp, float* __restrict__ out)
{
    __shared__ unsigned short Albs[2][128 * 64];
    __shared__ unsigned short Blbs[2][128 * 64];

    const int tid = threadIdx.x;
    const int rt = blockIdx.x;          // 256
    const int ct = blockIdx.y;          // 2

    const int wid = tid >> 6, l = tid & 63;
    const int wr = wid >> 1, wc = wid & 1;

    int srow[4], scol8[4];
#pragma unroll
    for (int it = 0; it < 4; ++it) {
        const int chunk = it * 256 + tid;
        srow[it] = chunk >> 3;
        scol8[it] = ((chunk & 7) ^ (srow[it] & 7)) * 8;
    }

#define STAGE(buf, ks)                                                                  \
    {                                                                                   \
        _Pragma("unroll")                                                               \
        for (int it = 0; it < 4; ++it) {                                                \
            const unsigned short* ga = Ab + ((size_t)(rt * 128 + srow[it])) * 256       \
                                          + (ks) * 64 + scol8[it];                      \
            const unsigned short* gb = Btp + ((size_t)(ct * 128 + srow[it])) * 256      \
                                           + (ks) * 64 + scol8[it];                     \
            __builtin_amdgcn_global_load_lds(                                           \
                (const __attribute__((address_space(1))) unsigned int*)(const void*)ga, \
                (__attribute__((address_space(3))) unsigned int*)(void*)                \
                    ((char*)&Albs[buf][0] + (it * 256 + tid) * 16), 16, 0, 0);          \
            __builtin_amdgcn_global_load_lds(                                           \
                (const __attribute__((address_space(1))) unsigned int*)(const void*)gb, \
                (__attribute__((address_space(3))) unsigned int*)(void*)                \
                    ((char*)&Blbs[buf][0] + (it * 256 + tid) * 16), 16, 0, 0);          \
        }                                                                               \
    }

    f32x4 acc[4][4];
#pragma unroll
    for (int m = 0; m < 4; ++m)
#pragma unroll
        for (int n = 0; n < 4; ++n) acc[m][n] = (f32x4){0.f, 0.f, 0.f, 0.f};

    STAGE(0, 0);
    __syncthreads();

    for (int ks = 0; ks < 4; ++ks) {
        const int cur = ks & 1;
        if (ks < 3) STAGE(cur ^ 1, ks + 1);
#pragma unroll
        for (int kk = 0; kk < 2; ++kk) {
            bf16x8 a[4], b[4];
#pragma unroll
            for (int m = 0; m < 4; ++m) {
                const int row = wr * 64 + m * 16 + (l & 15);
                const int byte = row * 128 + ((((kk * 4 + (l >> 4)) * 16)) ^ ((row & 7) << 4));
                a[m] = *(const bf16x8*)((const char*)&Albs[cur][0] + byte);
            }
#pragma unroll
            for (int n = 0; n < 4; ++n) {
                const int row = wc * 64 + n * 16 + (l & 15);
                const int byte = row * 128 + ((((kk * 4 + (l >> 4)) * 16)) ^ ((row & 7) << 4));
                b[n] = *(const bf16x8*)((const char*)&Blbs[cur][0] + byte);
            }
#pragma unroll
            for (int m = 0; m < 4; ++m)
#pragma unroll
                for (int n = 0; n < 4; ++n)
                    acc[m][n] = __builtin_amdgcn_mfma_f32_16x16x32_bf16(a[m], b[n], acc[m][n], 0, 0, 0);
        }
        __syncthreads();
    }

#pragma unroll
    for (int n = 0; n < 4; ++n) {
        const int col = ct * 128 + wc * 64 + n * 16 + (l & 15);
        const float bpv = bp[col];
#pragma unroll
        for (int m = 0; m < 4; ++m) {
#pragma unroll
            for (int j = 0; j < 4; ++j) {
                const int row = rt * 128 + wr * 64 + m * 16 + (l >> 4) * 4 + j;
                out[(size_t)row * 256 + col] = acc[m][n][j] + bpv;
            }
        }
    }
#undef STAGE
}

// ---------------- K2: kNN v5 — 32 q/block, tight tau (16th of 24-union) ----
// Pass A: 8 thr/query chain-3 -> 24-union; merge takes 16th smallest -> tau.
// Pass B: 16 reg-candidates/thread vs 32 queries, LDS append (CAP 160).
// Tail: exact f64 re-rank of survivors (bit-identical comparator).
__global__ __launch_bounds__(256) void knn_kernel(
    const float* __restrict__ pos, int* __restrict__ idx_out)
{
    __shared__ unsigned int pxy[Nv];             // 16 KB fp16 x|y
    __shared__ unsigned short pzs[Nv];           // 8 KB fp16 z
    __shared__ float4 qf[32];                    // qx,qy,qz,tau
    __shared__ unsigned int akeys[256 * 3];      // 3 KB pass-A survivors
    __shared__ unsigned int cnt[32];
    __shared__ unsigned short bufs[32 * CAPv];   // 10 KB survivor indices

    const int tid = threadIdx.x;
    const int ql = tid >> 3;                 // 0..31 query within block
    const int s  = tid & 7;                  // segment 0..7
    const int q  = blockIdx.x * 32 + ql;
    const int b  = q >> 12;
    const int n  = q & (Nv - 1);
    const float* pb = pos + (size_t)b * Nv * 3;

    for (int i = tid; i < Nv; i += 256) {
        const float px = pb[3 * i], py = pb[3 * i + 1], pz = pb[3 * i + 2];
        pxy[i] = (unsigned int)f2h(px) | ((unsigned int)f2h(py) << 16);
        pzs[i] = f2h(pz);
    }
    __syncthreads();

    const unsigned int sxy = pxy[n];
    const float qx = f16lo(sxy), qy = f16hi(sxy);
    const float qz = f16lo((unsigned int)pzs[n]);

    // ---- Pass A: chain-3 over candidates j = 16t+2s, 16t+2s+1 ----
    unsigned int c0k = 0xFFFFFFFFu, c1k = 0xFFFFFFFFu, c2k = 0xFFFFFFFFu;
    for (int t = 0; t < 256; ++t) {
        const int j = 16 * t + 2 * s;
        const uint2 xy = *(const uint2*)&pxy[j];
        const unsigned int zz = *(const unsigned int*)&pzs[j];
        const float dx0 = f16lo(xy.x) - qx, dy0 = f16hi(xy.x) - qy, dz0 = f16lo(zz) - qz;
        const float dx1 = f16lo(xy.y) - qx, dy1 = f16hi(xy.y) - qy, dz1 = f16hi(zz) - qz;
        const float d0 = fmaf(dx0, dx0, fmaf(dy0, dy0, dz0 * dz0));
        const float d1 = fmaf(dx1, dx1, fmaf(dy1, dy1, dz1 * dz1));
        const unsigned int k0 = (__float_as_uint(d0) & 0xFFFFF000u) | (unsigned)j;
        const unsigned int k1 = (__float_as_uint(d1) & 0xFFFFF000u) | (unsigned)(j + 1);
        const unsigned int klo = umin32(k0, k1);
        const unsigned int khi = umax32(k0, k1);
        if (klo < c2k) {
            {
                const unsigned int lo = umin32(c0k, klo);
                const unsigned int hi = umax32(c0k, klo);
                c0k = lo;
                const unsigned int lo1 = umin32(c1k, hi);
                const unsigned int hi1 = umax32(c1k, hi);
                c1k = lo1;
                c2k = umin32(c2k, hi1);
            }
            if (khi < c2k) {
                const unsigned int lo = umin32(c0k, khi);
                const unsigned int hi = umax32(c0k, khi);
                c0k = lo;
                const unsigned int lo1 = umin32(c1k, hi);
                const unsigned int hi1 = umax32(c1k, hi);
                c1k = lo1;
                c2k = umin32(c2k, hi1);
            }
        }
    }
    akeys[tid * 3 + 0] = c0k;
    akeys[tid * 3 + 1] = c1k;
    akeys[tid * 3 + 2] = c2k;
    __syncthreads();

    // ---- merge: 16th smallest of the 24-union -> tau ----
    if (tid < 32) {
        unsigned int sel16[16];
#pragma unroll
        for (int i = 0; i < 16; ++i) sel16[i] = 0xFFFFFFFFu;
        for (int s8 = 0; s8 < 8; ++s8) {
#pragma unroll
            for (int i3 = 0; i3 < 3; ++i3) {
                unsigned int cand = akeys[(8 * tid + s8) * 3 + i3];
                if (cand < sel16[15]) {
#pragma unroll
                    for (int i = 0; i < 16; ++i) {
                        const unsigned int lo = umin32(sel16[i], cand);
                        cand = umax32(sel16[i], cand);
                        sel16[i] = lo;
                    }
                }
            }
        }
        const float tau = __uint_as_float(sel16[15] & 0xFFFFF000u) * 1.12f + 1e-20f;
        const int n2 = (blockIdx.x * 32 + tid) & (Nv - 1);
        const unsigned int qp = pxy[n2];
        qf[tid] = make_float4(f16lo(qp), f16hi(qp), f16lo((unsigned int)pzs[n2]), tau);
        cnt[tid] = 0;
    }
    __syncthreads();

    // ---- Pass B: 16 register candidates vs 32 queries ----
    float cx[16], cy[16], cz[16];
#pragma unroll
    for (int k = 0; k < 16; ++k) {
        const unsigned int u = pxy[tid + (k << 8)];
        cx[k] = f16lo(u); cy[k] = f16hi(u);
        cz[k] = f16lo((unsigned int)pzs[tid + (k << 8)]);
    }
    for (int q2 = 0; q2 < 32; ++q2) {
        const float4 Q = qf[q2];
#pragma unroll
        for (int k = 0; k < 16; ++k) {
            const float dx = cx[k] - Q.x, dy = cy[k] - Q.y, dz = cz[k] - Q.z;
            const float d2 = fmaf(dx, dx, fmaf(dy, dy, dz * dz));
            if (d2 < Q.w) {
                const unsigned int slot = atomicAdd(&cnt[q2], 1u);
                if (slot < CAPv) bufs[q2 * CAPv + slot] = (unsigned short)(tid + (k << 8));
            }
        }
    }
    __syncthreads();

    // ---- Tail: exact f64 re-rank (identical comparator to prior rounds) ---
    if (tid < 32) {
        const int q2 = blockIdx.x * 32 + tid;
        const int n2 = q2 & (Nv - 1);
        const int b2 = q2 >> 12;
        const float* pb2 = pos + (size_t)b2 * Nv * 3;
        const double qxd = (double)pb2[3 * n2];
        const double qyd = (double)pb2[3 * n2 + 1];
        const double qzd = (double)pb2[3 * n2 + 2];
        const double a2qd = qxd * qxd + qyd * qyd + qzd * qzd;
        int c = (int)cnt[tid]; if (c > CAPv) c = CAPv;
        unsigned long long sel[Kv];
#pragma unroll
        for (int i = 0; i < Kv; ++i) sel[i] = ~0ull;
        for (int t = 0; t < c; ++t) {
            const int j = bufs[tid * CAPv + t];
            const double cxd = (double)pb2[3 * j];
            const double cyd = (double)pb2[3 * j + 1];
            const double czd = (double)pb2[3 * j + 2];
            const double a2cd = cxd * cxd + cyd * cyd + czd * czd;
            const double ddot = qxd * cxd + qyd * cyd + qzd * czd;
            double dv = (a2qd + a2cd) - 2.0 * ddot;
            dv = (dv < 0.0) ? 0.0 : dv;
            if (j == n2) dv = 0.0;
            union { double d; unsigned long long u; } cv; cv.d = dv;
            const unsigned long long key = (cv.u & ~0xFFFULL) | (unsigned long long)j;
            if (key < sel[Kv - 1]) {
                unsigned long long cc = key;
#pragma unroll
                for (int i = 0; i < Kv; ++i) {
                    const unsigned long long lo = (sel[i] < cc) ? sel[i] : cc;
                    const unsigned long long hi = (sel[i] < cc) ? cc : sel[i];
                    sel[i] = lo; cc = hi;
                }
            }
        }
#pragma unroll
        for (int i = 0; i < Kv; ++i)
            idx_out[(long)q2 * Kv + i] = (int)(sel[i] & 0xFFFull);
    }
}

// ---------------- K3: gather + attention + RPE bias -> o (bf16, in-place) --
__global__ __launch_bounds__(256) void attn_core_kernel(
    unsigned short* __restrict__ qb, const unsigned short* __restrict__ kb,
    const unsigned short* __restrict__ vb, const int* __restrict__ idx,
    const float* __restrict__ pos, const float* __restrict__ W1,
    const float* __restrict__ b1, const float* __restrict__ w2sum,
    const float* __restrict__ b2sum)
{
    __shared__ float q_lds[8][Cv];
    __shared__ float lg[8][Kv];
    __shared__ float wgt[8][Kv];
    __shared__ int idx_l[8][Kv];
    __shared__ float W1l[3 * RPEv];
    __shared__ float b1l[RPEv], w2s[RPEv];
    __shared__ float posq[24];
    __shared__ float b2s_l;

    const int tid = threadIdx.x;
    const long r0 = (long)blockIdx.x * 8;   // 8 query rows per block
    const int bq = (int)(r0 >> 12);

    {
        float* ql = &q_lds[0][0];
        for (int i = tid; i < 8 * Cv; i += 256) ql[i] = bf2f(qb[r0 * Cv + i]);
    }
    if (tid < 128) ((int*)idx_l)[tid] = idx[r0 * Kv + tid];
    if (tid < 3 * RPEv) W1l[tid] = W1[tid];
    if (tid < RPEv) { b1l[tid] = b1[tid]; w2s[tid] = w2sum[tid]; }
    if (tid < 24) posq[tid] = pos[r0 * 3 + tid];
    if (tid == 0) b2s_l = *b2sum;
    __syncthreads();

    const int g = tid >> 4, l = tid & 15;   // 16 groups x 16 lanes
    for (int r = 0; r < 8; ++r) {
        const int nb = idx_l[r][g];
        const long gi = (long)bq * Nv + nb;
        const unsigned short* kr = kb + gi * Cv + l * 16;
        const float* qq = &q_lds[r][l * 16];
        const uint4 kA = *(const uint4*)kr;
        const uint4 kB = *(const uint4*)(kr + 8);
        float part = 0.f;
        part = fmaf(qq[0],  bf2f(kA.x & 0xffffu), part);
        part = fmaf(qq[1],  bf2f(kA.x >> 16),     part);
        part = fmaf(qq[2],  bf2f(kA.y & 0xffffu), part);
        part = fmaf(qq[3],  bf2f(kA.y >> 16),     part);
        part = fmaf(qq[4],  bf2f(kA.z & 0xffffu), part);
        part = fmaf(qq[5],  bf2f(kA.z >> 16),     part);
        part = fmaf(qq[6],  bf2f(kA.w & 0xffffu), part);
        part = fmaf(qq[7],  bf2f(kA.w >> 16),     part);
        part = fmaf(qq[8],  bf2f(kB.x & 0xffffu), part);
        part = fmaf(qq[9],  bf2f(kB.x >> 16),     part);
        part = fmaf(qq[10], bf2f(kB.y & 0xffffu), part);
        part = fmaf(qq[11], bf2f(kB.y >> 16),     part);
        part = fmaf(qq[12], bf2f(kB.z & 0xffffu), part);
        part = fmaf(qq[13], bf2f(kB.z >> 16),     part);
        part = fmaf(qq[14], bf2f(kB.w & 0xffffu), part);
        part = fmaf(qq[15], bf2f(kB.w >> 16),     part);
        const float rx = posq[r * 3 + 0] - pos[gi * 3 + 0];
        const float ry = posq[r * 3 + 1] - pos[gi * 3 + 1];
        const float rz = posq[r * 3 + 2] - pos[gi * 3 + 2];
#pragma unroll
        for (int u4 = 0; u4 < 4; ++u4) {
            const int u = l * 4 + u4;
            float h = fmaf(rx, W1l[u], fmaf(ry, W1l[RPEv + u], fmaf(rz, W1l[2 * RPEv + u], b1l[u])));
            h = fmaxf(h, 0.f);
            part = fmaf(h, w2s[u], part);
        }
        part += __shfl_xor(part, 8);
        part += __shfl_xor(part, 4);
        part += __shfl_xor(part, 2);
        part += __shfl_xor(part, 1);
        if (l == 0) lg[r][g] = (part + b2s_l) * 0.0625f;
    }
    __syncthreads();
    if (tid < 128) {
        const int rr = tid >> 4, gg = tid & 15;
        const float v = lg[rr][gg];
        float m = v;
        m = fmaxf(m, __shfl_xor(m, 8)); m = fmaxf(m, __shfl_xor(m, 4));
        m = fmaxf(m, __shfl_xor(m, 2)); m = fmaxf(m, __shfl_xor(m, 1));
        const float e = __expf(v - m);
        float ssum = e;
        ssum += __shfl_xor(ssum, 8); ssum += __shfl_xor(ssum, 4);
        ssum += __shfl_xor(ssum, 2); ssum += __shfl_xor(ssum, 1);
        wgt[rr][gg] = e / ssum;
    }
    __syncthreads();
    {
        const int c = tid;
        for (int r = 0; r < 8; ++r) {
            float acc = 0.f;
#pragma unroll
            for (int t = 0; t < Kv; ++t) {
                const long gi = (long)bq * Nv + idx_l[r][t];
                acc = fmaf(wgt[r][t], bf2f((unsigned)vb[gi * Cv + c]), acc);
            }
            // in-place: overwrite this block's own q rows with o (bf16)
            qb[(r0 + r) * Cv + c] = f2bf(acc);
        }
    }
}

extern "C" void kernel_launch(void* const* d_in, const int* in_sizes, int n_in,
                              void* d_out, int out_size, void* d_ws, size_t ws_size,
                              hipStream_t stream) {
    (void)in_sizes; (void)n_in; (void)out_size; (void)ws_size;
    const float* x      = (const float*)d_in[0];
    const float* pos    = (const float*)d_in[1];
    const float* Wq     = (const float*)d_in[2];
    const float* Wk     = (const float*)d_in[3];
    const float* Wv     = (const float*)d_in[4];
    const float* W1     = (const float*)d_in[5];
    const float* b1     = (const float*)d_in[6];
    const float* W2     = (const float*)d_in[7];
    const float* b2     = (const float*)d_in[8];
    const float* Wp     = (const float*)d_in[9];
    const float* bp     = (const float*)d_in[10];
    const float* gq     = (const float*)d_in[11];
    const float* betaq  = (const float*)d_in[12];
    const float* gkv    = (const float*)d_in[13];
    const float* betakv = (const float*)d_in[14];
    float* out = (float*)d_out;

    char* ws = (char*)d_ws;
    unsigned short* qb = (unsigned short*)(ws);               // 3 x 16 MiB bf16 q/k/v
    unsigned short* kb = (unsigned short*)(ws + 16777216);
    unsigned short* vb = (unsigned short*)(ws + 33554432);
    int*   idx   = (int*)  (ws + 50331648);                   // 2 MiB
    unsigned short* Bt = (unsigned short*)(ws + 52428800);    // 1024*256*2 = 512 KiB
    float* w2sum = (float*)(ws + 52953088);
    float* b2sum = (float*)(ws + 52953344);

    unsigned short* Aq  = (unsigned short*)d_out;             // d_out as scratch
    unsigned short* Akv = (unsigned short*)d_out + 8388608;

    hipLaunchKernelGGL(prep_kernel, dim3(1), dim3(64), 0, stream, W2, b2, w2sum, b2sum);
    hipLaunchKernelGGL(wcast_kernel, dim3(1024), dim3(256), 0, stream, Wq, Wk, Wv, Wp, Bt);
    hipLaunchKernelGGL(ln_cast_kernel, dim3(4096), dim3(256), 0, stream,
                       x, gq, betaq, gkv, betakv, Aq, Akv);
    hipLaunchKernelGGL(gemm_qkv_kernel, dim3(256, 6), dim3(256), 0, stream,
                       Aq, Akv, Bt, qb, kb, vb);
    hipLaunchKernelGGL(knn_kernel, dim3(1024), dim3(256), 0, stream, pos, idx);
    hipLaunchKernelGGL(attn_core_kernel, dim3(4096), dim3(256), 0, stream,
                       qb, kb, vb, idx, pos, W1, b1, w2sum, b2sum);
    // o (bf16, in qb) @ Wp^T + bp -> f32 out
    hipLaunchKernelGGL(gemm_proj_kernel, dim3(256, 2), dim3(256), 0, stream,
                       qb, Bt + 768 * 256, bp, out);
}

// Round 7
// 208.026 us; speedup vs baseline: 6.9288x; 1.1460x over previous
//
#include <hip/hip_runtime.h>
#include <hip/hip_bf16.h>
#include <stdint.h>

#define Bv 8
#define Nv 4096
#define Cv 256
#define Kv 16
#define RPEv 64
#define CAPv 160

typedef short bf16x8 __attribute__((ext_vector_type(8)));
typedef float f32x4 __attribute__((ext_vector_type(4)));
typedef _Float16 half2v __attribute__((ext_vector_type(2)));
typedef unsigned short u16x2 __attribute__((ext_vector_type(2)));

static __device__ __forceinline__ float bf2f(unsigned int u16) {
    union { unsigned int i; float f; } v; v.i = u16 << 16; return v.f;
}
static __device__ __forceinline__ unsigned short f2bf(float f) {
    union { float f; unsigned int i; } v; v.f = f;
    unsigned int x = v.i;
    return (unsigned short)((x + 0x7fffu + ((x >> 16) & 1u)) >> 16);
}
static __device__ __forceinline__ unsigned int umin32(unsigned int a, unsigned int b) { return a < b ? a : b; }
static __device__ __forceinline__ unsigned int umax32(unsigned int a, unsigned int b) { return a > b ? a : b; }
static __device__ __forceinline__ unsigned short f2h(float f) {
    _Float16 h = (_Float16)f; return __builtin_bit_cast(unsigned short, h);
}
static __device__ __forceinline__ float h2f(unsigned int u) {
    _Float16 h = __builtin_bit_cast(_Float16, (unsigned short)(u & 0xffffu)); return (float)h;
}
static __device__ __forceinline__ half2v bch2(unsigned int u) { return __builtin_bit_cast(half2v, u); }
static __device__ __forceinline__ unsigned int bcu32(u16x2 v) { return __builtin_bit_cast(unsigned int, v); }

// ---------------- K0: tiny prep (w2sum = colsum over C of W2, b2sum) -------
__global__ void prep_kernel(const float* __restrict__ W2, const float* __restrict__ b2,
                            float* __restrict__ w2sum, float* __restrict__ b2sum) {
    const int u = threadIdx.x;
    if (u < RPEv) {
        float s = 0.f;
        for (int c = 0; c < Cv; ++c) s += W2[u * Cv + c];
        w2sum[u] = s;
    }
    if (u == 0) {
        float s = 0.f;
        for (int c = 0; c < Cv; ++c) s += b2[c];
        *b2sum = s;
    }
}

// ---------------- K0b: weight transpose-cast -> Bt[1024][256] bf16 ---------
// rows 0-255: Wq^T, 256-511: Wk^T, 512-767: Wv^T, 768-1023: Wp^T
__global__ __launch_bounds__(256) void wcast_kernel(
    const float* __restrict__ Wq, const float* __restrict__ Wk,
    const float* __restrict__ Wv, const float* __restrict__ Wp,
    unsigned short* __restrict__ Bt)
{
    const int r = blockIdx.x;       // 0..1023
    const int t = threadIdx.x;      // k
    const float* W = (r < 256) ? Wq : (r < 512) ? Wk : (r < 768) ? Wv : Wp;
    const int n = r & 255;
    Bt[r * 256 + t] = f2bf(W[t * 256 + n]);
}

// ---------------- K1a: dual LayerNorm + bf16 cast (A matrices) -------------
__global__ __launch_bounds__(256) void ln_cast_kernel(
    const float* __restrict__ x,
    const float* __restrict__ gq, const float* __restrict__ bq,
    const float* __restrict__ gkv, const float* __restrict__ bkv,
    unsigned short* __restrict__ Aq, unsigned short* __restrict__ Akv)
{
    const int tid = threadIdx.x;
    const long r0 = (long)blockIdx.x * 8;
    const int row = tid >> 5;          // 32 threads per row
    const int c0 = (tid & 31) * 8;     // 8 consecutive channels each
    const float* xr = x + (r0 + row) * Cv + c0;
    float xv[8];
    *(float4*)&xv[0] = *(const float4*)xr;
    *(float4*)&xv[4] = *(const float4*)(xr + 4);
    float s = 0.f, s2 = 0.f;
#pragma unroll
    for (int i = 0; i < 8; ++i) { s += xv[i]; s2 = fmaf(xv[i], xv[i], s2); }
#pragma unroll
    for (int m = 16; m >= 1; m >>= 1) { s += __shfl_xor(s, m); s2 += __shfl_xor(s2, m); }
    const float mean = s * (1.f / Cv);
    const float var = fmaf(-mean, mean, s2 * (1.f / Cv));
    const float rs = rsqrtf(fmaxf(var, 0.f) + 1e-5f);
    unsigned int pq[4], pk[4];
#pragma unroll
    for (int i = 0; i < 4; ++i) {
        const int c = c0 + 2 * i;
        const float h0 = (xv[2 * i] - mean) * rs;
        const float h1 = (xv[2 * i + 1] - mean) * rs;
        const unsigned int q0 = f2bf(fmaf(h0, gq[c], bq[c]));
        const unsigned int q1 = f2bf(fmaf(h1, gq[c + 1], bq[c + 1]));
        const unsigned int k0 = f2bf(fmaf(h0, gkv[c], bkv[c]));
        const unsigned int k1 = f2bf(fmaf(h1, gkv[c + 1], bkv[c + 1]));
        pq[i] = q0 | (q1 << 16);
        pk[i] = k0 | (k1 << 16);
    }
    const long off = (r0 + row) * Cv + c0;
    *(uint4*)&Aq[off]  = make_uint4(pq[0], pq[1], pq[2], pq[3]);
    *(uint4*)&Akv[off] = make_uint4(pk[0], pk[1], pk[2], pk[3]);
}

// ---------------- K1b: bf16 MFMA GEMM  C[32768 x 768] = A @ W (bf16 out) ---
__global__ __launch_bounds__(256) void gemm_qkv_kernel(
    const unsigned short* __restrict__ Aq, const unsigned short* __restrict__ Akv,
    const unsigned short* __restrict__ Bt,
    unsigned short* __restrict__ qo, unsigned short* __restrict__ ko,
    unsigned short* __restrict__ vo)
{
    __shared__ unsigned short Albs[2][128 * 64];
    __shared__ unsigned short Blbs[2][128 * 64];

    const int tid = threadIdx.x;
    const int rt = blockIdx.x;          // row tile: 256
    const int ct = blockIdx.y;          // col tile: 6
    const unsigned short* A = (ct < 2) ? Aq : Akv;
    const int mat = ct >> 1;
    unsigned short* outp = (mat == 0) ? qo : (mat == 1) ? ko : vo;
    const int colInMat = (ct & 1) * 128;

    const int wid = tid >> 6, l = tid & 63;
    const int wr = wid >> 1, wc = wid & 1;

    int srow[4], scol8[4];
#pragma unroll
    for (int it = 0; it < 4; ++it) {
        const int chunk = it * 256 + tid;
        srow[it] = chunk >> 3;
        scol8[it] = ((chunk & 7) ^ (srow[it] & 7)) * 8;
    }

#define STAGE(buf, ks)                                                                  \
    {                                                                                   \
        _Pragma("unroll")                                                               \
        for (int it = 0; it < 4; ++it) {                                                \
            const unsigned short* ga = A + ((size_t)(rt * 128 + srow[it])) * 256        \
                                         + (ks) * 64 + scol8[it];                       \
            const unsigned short* gb = Bt + ((size_t)(ct * 128 + srow[it])) * 256       \
                                          + (ks) * 64 + scol8[it];                      \
            __builtin_amdgcn_global_load_lds(                                           \
                (const __attribute__((address_space(1))) unsigned int*)(const void*)ga, \
                (__attribute__((address_space(3))) unsigned int*)(void*)                \
                    ((char*)&Albs[buf][0] + (it * 256 + tid) * 16), 16, 0, 0);          \
            __builtin_amdgcn_global_load_lds(                                           \
                (const __attribute__((address_space(1))) unsigned int*)(const void*)gb, \
                (__attribute__((address_space(3))) unsigned int*)(void*)                \
                    ((char*)&Blbs[buf][0] + (it * 256 + tid) * 16), 16, 0, 0);          \
        }                                                                               \
    }

    f32x4 acc[4][4];
#pragma unroll
    for (int m = 0; m < 4; ++m)
#pragma unroll
        for (int n = 0; n < 4; ++n) acc[m][n] = (f32x4){0.f, 0.f, 0.f, 0.f};

    STAGE(0, 0);
    __syncthreads();

    for (int ks = 0; ks < 4; ++ks) {
        const int cur = ks & 1;
        if (ks < 3) STAGE(cur ^ 1, ks + 1);
#pragma unroll
        for (int kk = 0; kk < 2; ++kk) {
            bf16x8 a[4], b[4];
#pragma unroll
            for (int m = 0; m < 4; ++m) {
                const int row = wr * 64 + m * 16 + (l & 15);
                const int byte = row * 128 + ((((kk * 4 + (l >> 4)) * 16)) ^ ((row & 7) << 4));
                a[m] = *(const bf16x8*)((const char*)&Albs[cur][0] + byte);
            }
#pragma unroll
            for (int n = 0; n < 4; ++n) {
                const int row = wc * 64 + n * 16 + (l & 15);
                const int byte = row * 128 + ((((kk * 4 + (l >> 4)) * 16)) ^ ((row & 7) << 4));
                b[n] = *(const bf16x8*)((const char*)&Blbs[cur][0] + byte);
            }
#pragma unroll
            for (int m = 0; m < 4; ++m)
#pragma unroll
                for (int n = 0; n < 4; ++n)
                    acc[m][n] = __builtin_amdgcn_mfma_f32_16x16x32_bf16(a[m], b[n], acc[m][n], 0, 0, 0);
        }
        __syncthreads();
    }

#pragma unroll
    for (int m = 0; m < 4; ++m) {
#pragma unroll
        for (int n = 0; n < 4; ++n) {
#pragma unroll
            for (int j = 0; j < 4; ++j) {
                const int row = rt * 128 + wr * 64 + m * 16 + (l >> 4) * 4 + j;
                const int col = colInMat + wc * 64 + n * 16 + (l & 15);
                outp[(size_t)row * 256 + col] = f2bf(acc[m][n][j]);
            }
        }
    }
#undef STAGE
}

// ---------------- K4: proj GEMM  out[32768 x 256] = o @ Wp^T + bp (f32) ----
__global__ __launch_bounds__(256) void gemm_proj_kernel(
    const unsigned short* __restrict__ Ab, const unsigned short* __restrict__ Btp,
    const float* __restrict__ bp, float* __restrict__ out)
{
    __shared__ unsigned short Albs[2][128 * 64];
    __shared__ unsigned short Blbs[2][128 * 64];

    const int tid = threadIdx.x;
    const int rt = blockIdx.x;          // 256
    const int ct = blockIdx.y;          // 2

    const int wid = tid >> 6, l = tid & 63;
    const int wr = wid >> 1, wc = wid & 1;

    int srow[4], scol8[4];
#pragma unroll
    for (int it = 0; it < 4; ++it) {
        const int chunk = it * 256 + tid;
        srow[it] = chunk >> 3;
        scol8[it] = ((chunk & 7) ^ (srow[it] & 7)) * 8;
    }

#define STAGE(buf, ks)                                                                  \
    {                                                                                   \
        _Pragma("unroll")                                                               \
        for (int it = 0; it < 4; ++it) {                                                \
            const unsigned short* ga = Ab + ((size_t)(rt * 128 + srow[it])) * 256       \
                                          + (ks) * 64 + scol8[it];                      \
            const unsigned short* gb = Btp + ((size_t)(ct * 128 + srow[it])) * 256      \
                                           + (ks) * 64 + scol8[it];                     \
            __builtin_amdgcn_global_load_lds(                                           \
                (const __attribute__((address_space(1))) unsigned int*)(const void*)ga, \
                (__attribute__((address_space(3))) unsigned int*)(void*)                \
                    ((char*)&Albs[buf][0] + (it * 256 + tid) * 16), 16, 0, 0);          \
            __builtin_amdgcn_global_load_lds(                                           \
                (const __attribute__((address_space(1))) unsigned int*)(const void*)gb, \
                (__attribute__((address_space(3))) unsigned int*)(void*)                \
                    ((char*)&Blbs[buf][0] + (it * 256 + tid) * 16), 16, 0, 0);          \
        }                                                                               \
    }

    f32x4 acc[4][4];
#pragma unroll
    for (int m = 0; m < 4; ++m)
#pragma unroll
        for (int n = 0; n < 4; ++n) acc[m][n] = (f32x4){0.f, 0.f, 0.f, 0.f};

    STAGE(0, 0);
    __syncthreads();

    for (int ks = 0; ks < 4; ++ks) {
        const int cur = ks & 1;
        if (ks < 3) STAGE(cur ^ 1, ks + 1);
#pragma unroll
        for (int kk = 0; kk < 2; ++kk) {
            bf16x8 a[4], b[4];
#pragma unroll
            for (int m = 0; m < 4; ++m) {
                const int row = wr * 64 + m * 16 + (l & 15);
                const int byte = row * 128 + ((((kk * 4 + (l >> 4)) * 16)) ^ ((row & 7) << 4));
                a[m] = *(const bf16x8*)((const char*)&Albs[cur][0] + byte);
            }
#pragma unroll
            for (int n = 0; n < 4; ++n) {
                const int row = wc * 64 + n * 16 + (l & 15);
                const int byte = row * 128 + ((((kk * 4 + (l >> 4)) * 16)) ^ ((row & 7) << 4));
                b[n] = *(const bf16x8*)((const char*)&Blbs[cur][0] + byte);
            }
#pragma unroll
            for (int m = 0; m < 4; ++m)
#pragma unroll
                for (int n = 0; n < 4; ++n)
                    acc[m][n] = __builtin_amdgcn_mfma_f32_16x16x32_bf16(a[m], b[n], acc[m][n], 0, 0, 0);
        }
        __syncthreads();
    }

#pragma unroll
    for (int n = 0; n < 4; ++n) {
        const int col = ct * 128 + wc * 64 + n * 16 + (l & 15);
        const float bpv = bp[col];
#pragma unroll
        for (int m = 0; m < 4; ++m) {
#pragma unroll
            for (int j = 0; j < 4; ++j) {
                const int row = rt * 128 + wr * 64 + m * 16 + (l >> 4) * 4 + j;
                out[(size_t)row * 256 + col] = acc[m][n][j] + bpv;
            }
        }
    }
#undef STAGE
}

// ---------------- K2: kNN v6 — packed-fp16 branchless scan -----------------
// Pass A: 8 thr/query, packed-pair distances (v_pk), branchless packed
//         chain-3 per lane -> 48-union; merge takes 16th smallest -> tau.
// Pass B: 8 packed reg-pairs/thread vs 32 queries, integer-domain compare.
// Tail: exact f64 re-rank of survivors (bit-identical comparator).
__global__ __launch_bounds__(256) void knn_kernel(
    const float* __restrict__ pos, int* __restrict__ idx_out)
{
    __shared__ uint2 pxy2[Nv / 2];               // 16 KB fp16 (x0|x1, y0|y1)
    __shared__ unsigned int pz2[Nv / 2];         // 8 KB fp16 (z0|z1)
    __shared__ uint4 qu[32];                     // qx_pk, qy_pk, qz_pk, tau_u16
    __shared__ unsigned int akeys[256 * 3];      // 3 KB pass-A packed chains
    __shared__ unsigned int cnt[32];
    __shared__ unsigned short bufs[32 * CAPv];   // 10 KB survivor indices

    const int tid = threadIdx.x;
    const int ql = tid >> 3;                 // 0..31 query within block
    const int s  = tid & 7;                  // segment 0..7
    const int q  = blockIdx.x * 32 + ql;
    const int b  = q >> 12;
    const int n  = q & (Nv - 1);
    const float* pb = pos + (size_t)b * Nv * 3;

    for (int i = tid; i < Nv / 2; i += 256) {
        const float* pp = pb + 6 * i;
        const float2 u0 = *(const float2*)pp;
        const float2 u1 = *(const float2*)(pp + 2);
        const float2 u2 = *(const float2*)(pp + 4);
        const unsigned int x0 = f2h(u0.x), y0 = f2h(u0.y), z0 = f2h(u1.x);
        const unsigned int x1 = f2h(u1.y), y1 = f2h(u2.x), z1 = f2h(u2.y);
        pxy2[i] = make_uint2(x0 | (x1 << 16), y0 | (y1 << 16));
        pz2[i] = z0 | (z1 << 16);
    }
    __syncthreads();

    // query packed regs (broadcast fp16 into both halves)
    const int pq = n >> 1;
    const int hq = (n & 1) * 16;
    const uint2 qxy = pxy2[pq];
    const unsigned int qzz = pz2[pq];
    const unsigned int hx = (qxy.x >> hq) & 0xffffu;
    const unsigned int hy = (qxy.y >> hq) & 0xffffu;
    const unsigned int hz = (qzz   >> hq) & 0xffffu;
    const half2v qxp = bch2(hx | (hx << 16));
    const half2v qyp = bch2(hy | (hy << 16));
    const half2v qzp = bch2(hz | (hz << 16));

    // ---- Pass A: branchless packed chain-3 over pairs p = 8t+s ----
    u16x2 ch0 = {0x7c00, 0x7c00}, ch1 = ch0, ch2 = ch0;   // +inf fp16
    for (int t = 0; t < 256; ++t) {
        const int p = 8 * t + s;
        const uint2 xy = pxy2[p];
        const unsigned int zz = pz2[p];
        const half2v dx = bch2(xy.x) - qxp;
        const half2v dy = bch2(xy.y) - qyp;
        const half2v dz = bch2(zz) - qzp;
        const half2v d2 = dx * dx + dy * dy + dz * dz;
        u16x2 k = __builtin_bit_cast(u16x2, d2);
        const u16x2 mn0 = __builtin_elementwise_min(ch0, k);
        const u16x2 mx0 = __builtin_elementwise_max(ch0, k);
        ch0 = mn0;
        const u16x2 mn1 = __builtin_elementwise_min(ch1, mx0);
        const u16x2 mx1 = __builtin_elementwise_max(ch1, mx0);
        ch1 = mn1;
        ch2 = __builtin_elementwise_min(ch2, mx1);
    }
    akeys[tid * 3 + 0] = bcu32(ch0);
    akeys[tid * 3 + 1] = bcu32(ch1);
    akeys[tid * 3 + 2] = bcu32(ch2);
    __syncthreads();

    // ---- merge: 16th smallest of the 48-union -> tau ----
    if (tid < 32) {
        unsigned int sel16[16];
#pragma unroll
        for (int i = 0; i < 16; ++i) sel16[i] = 0xFFFFFFFFu;
        for (int s8 = 0; s8 < 8; ++s8) {
#pragma unroll
            for (int i3 = 0; i3 < 3; ++i3) {
                const unsigned int v = akeys[(8 * tid + s8) * 3 + i3];
#pragma unroll
                for (int h = 0; h < 2; ++h) {
                    unsigned int cand = (h == 0) ? (v & 0xffffu) : (v >> 16);
                    if (cand < sel16[15]) {
#pragma unroll
                        for (int i = 0; i < 16; ++i) {
                            const unsigned int lo = umin32(sel16[i], cand);
                            cand = umax32(sel16[i], cand);
                            sel16[i] = lo;
                        }
                    }
                }
            }
        }
        const float tauf = h2f(sel16[15]) * 1.12f + 1e-9f;
        const unsigned int taub = f2h(tauf);
        const int n2 = (blockIdx.x * 32 + tid) & (Nv - 1);
        const int pq2 = n2 >> 1;
        const int hq2 = (n2 & 1) * 16;
        const uint2 qxy2 = pxy2[pq2];
        const unsigned int qzz2 = pz2[pq2];
        const unsigned int hx2 = (qxy2.x >> hq2) & 0xffffu;
        const unsigned int hy2 = (qxy2.y >> hq2) & 0xffffu;
        const unsigned int hz2 = (qzz2   >> hq2) & 0xffffu;
        qu[tid] = make_uint4(hx2 | (hx2 << 16), hy2 | (hy2 << 16),
                             hz2 | (hz2 << 16), taub);
        cnt[tid] = 0;
    }
    __syncthreads();

    // ---- Pass B: 8 packed register pairs (16 candidates) vs 32 queries ----
    uint2 cxy[8]; unsigned int czp[8];
#pragma unroll
    for (int k = 0; k < 8; ++k) {
        cxy[k] = pxy2[tid + (k << 8)];
        czp[k] = pz2[tid + (k << 8)];
    }
    for (int q2 = 0; q2 < 32; ++q2) {
        const uint4 Q = qu[q2];
        const half2v Qx = bch2(Q.x), Qy = bch2(Q.y), Qz = bch2(Q.z);
        const unsigned int taub = Q.w;
#pragma unroll
        for (int k = 0; k < 8; ++k) {
            const half2v dx = bch2(cxy[k].x) - Qx;
            const half2v dy = bch2(cxy[k].y) - Qy;
            const half2v dz = bch2(czp[k]) - Qz;
            const half2v d2 = dx * dx + dy * dy + dz * dz;
            const unsigned int bits = __builtin_bit_cast(unsigned int, d2);
            const unsigned int lo = bits & 0xffffu;
            const unsigned int hi = bits >> 16;
            const int p = tid + (k << 8);
            if (lo < taub) {
                const unsigned int slot = atomicAdd(&cnt[q2], 1u);
                if (slot < CAPv) bufs[q2 * CAPv + slot] = (unsigned short)(2 * p);
            }
            if (hi < taub) {
                const unsigned int slot = atomicAdd(&cnt[q2], 1u);
                if (slot < CAPv) bufs[q2 * CAPv + slot] = (unsigned short)(2 * p + 1);
            }
        }
    }
    __syncthreads();

    // ---- Tail: exact f64 re-rank (identical comparator to prior rounds) ---
    if (tid < 32) {
        const int q2 = blockIdx.x * 32 + tid;
        const int n2 = q2 & (Nv - 1);
        const int b2 = q2 >> 12;
        const float* pb2 = pos + (size_t)b2 * Nv * 3;
        const double qxd = (double)pb2[3 * n2];
        const double qyd = (double)pb2[3 * n2 + 1];
        const double qzd = (double)pb2[3 * n2 + 2];
        const double a2qd = qxd * qxd + qyd * qyd + qzd * qzd;
        int c = (int)cnt[tid]; if (c > CAPv) c = CAPv;
        unsigned long long sel[Kv];
#pragma unroll
        for (int i = 0; i < Kv; ++i) sel[i] = ~0ull;
        for (int t = 0; t < c; ++t) {
            const int j = bufs[tid * CAPv + t];
            const double cxd = (double)pb2[3 * j];
            const double cyd = (double)pb2[3 * j + 1];
            const double czd = (double)pb2[3 * j + 2];
            const double a2cd = cxd * cxd + cyd * cyd + czd * czd;
            const double ddot = qxd * cxd + qyd * cyd + qzd * czd;
            double dv = (a2qd + a2cd) - 2.0 * ddot;
            dv = (dv < 0.0) ? 0.0 : dv;
            if (j == n2) dv = 0.0;
            union { double d; unsigned long long u; } cv; cv.d = dv;
            const unsigned long long key = (cv.u & ~0xFFFULL) | (unsigned long long)j;
            if (key < sel[Kv - 1]) {
                unsigned long long cc = key;
#pragma unroll
                for (int i = 0; i < Kv; ++i) {
                    const unsigned long long lo = (sel[i] < cc) ? sel[i] : cc;
                    const unsigned long long hi = (sel[i] < cc) ? cc : sel[i];
                    sel[i] = lo; cc = hi;
                }
            }
        }
#pragma unroll
        for (int i = 0; i < Kv; ++i)
            idx_out[(long)q2 * Kv + i] = (int)(sel[i] & 0xFFFull);
    }
}

// ---------------- K3: gather + attention + RPE bias -> o (bf16, in-place) --
__global__ __launch_bounds__(256) void attn_core_kernel(
    unsigned short* __restrict__ qb, const unsigned short* __restrict__ kb,
    const unsigned short* __restrict__ vb, const int* __restrict__ idx,
    const float* __restrict__ pos, const float* __restrict__ W1,
    const float* __restrict__ b1, const float* __restrict__ w2sum,
    const float* __restrict__ b2sum)
{
    __shared__ float q_lds[8][Cv];
    __shared__ float lg[8][Kv];
    __shared__ float wgt[8][Kv];
    __shared__ int idx_l[8][Kv];
    __shared__ float W1l[3 * RPEv];
    __shared__ float b1l[RPEv], w2s[RPEv];
    __shared__ float posq[24];
    __shared__ float b2s_l;

    const int tid = threadIdx.x;
    const long r0 = (long)blockIdx.x * 8;   // 8 query rows per block
    const int bq = (int)(r0 >> 12);

    {
        float* ql = &q_lds[0][0];
        for (int i = tid; i < 8 * Cv; i += 256) ql[i] = bf2f(qb[r0 * Cv + i]);
    }
    if (tid < 128) ((int*)idx_l)[tid] = idx[r0 * Kv + tid];
    if (tid < 3 * RPEv) W1l[tid] = W1[tid];
    if (tid < RPEv) { b1l[tid] = b1[tid]; w2s[tid] = w2sum[tid]; }
    if (tid < 24) posq[tid] = pos[r0 * 3 + tid];
    if (tid == 0) b2s_l = *b2sum;
    __syncthreads();

    const int g = tid >> 4, l = tid & 15;   // 16 groups x 16 lanes
    for (int r = 0; r < 8; ++r) {
        const int nb = idx_l[r][g];
        const long gi = (long)bq * Nv + nb;
        const unsigned short* kr = kb + gi * Cv + l * 16;
        const float* qq = &q_lds[r][l * 16];
        const uint4 kA = *(const uint4*)kr;
        const uint4 kB = *(const uint4*)(kr + 8);
        float part = 0.f;
        part = fmaf(qq[0],  bf2f(kA.x & 0xffffu), part);
        part = fmaf(qq[1],  bf2f(kA.x >> 16),     part);
        part = fmaf(qq[2],  bf2f(kA.y & 0xffffu), part);
        part = fmaf(qq[3],  bf2f(kA.y >> 16),     part);
        part = fmaf(qq[4],  bf2f(kA.z & 0xffffu), part);
        part = fmaf(qq[5],  bf2f(kA.z >> 16),     part);
        part = fmaf(qq[6],  bf2f(kA.w & 0xffffu), part);
        part = fmaf(qq[7],  bf2f(kA.w >> 16),     part);
        part = fmaf(qq[8],  bf2f(kB.x & 0xffffu), part);
        part = fmaf(qq[9],  bf2f(kB.x >> 16),     part);
        part = fmaf(qq[10], bf2f(kB.y & 0xffffu), part);
        part = fmaf(qq[11], bf2f(kB.y >> 16),     part);
        part = fmaf(qq[12], bf2f(kB.z & 0xffffu), part);
        part = fmaf(qq[13], bf2f(kB.z >> 16),     part);
        part = fmaf(qq[14], bf2f(kB.w & 0xffffu), part);
        part = fmaf(qq[15], bf2f(kB.w >> 16),     part);
        const float rx = posq[r * 3 + 0] - pos[gi * 3 + 0];
        const float ry = posq[r * 3 + 1] - pos[gi * 3 + 1];
        const float rz = posq[r * 3 + 2] - pos[gi * 3 + 2];
#pragma unroll
        for (int u4 = 0; u4 < 4; ++u4) {
            const int u = l * 4 + u4;
            float h = fmaf(rx, W1l[u], fmaf(ry, W1l[RPEv + u], fmaf(rz, W1l[2 * RPEv + u], b1l[u])));
            h = fmaxf(h, 0.f);
            part = fmaf(h, w2s[u], part);
        }
        part += __shfl_xor(part, 8);
        part += __shfl_xor(part, 4);
        part += __shfl_xor(part, 2);
        part += __shfl_xor(part, 1);
        if (l == 0) lg[r][g] = (part + b2s_l) * 0.0625f;
    }
    __syncthreads();
    if (tid < 128) {
        const int rr = tid >> 4, gg = tid & 15;
        const float v = lg[rr][gg];
        float m = v;
        m = fmaxf(m, __shfl_xor(m, 8)); m = fmaxf(m, __shfl_xor(m, 4));
        m = fmaxf(m, __shfl_xor(m, 2)); m = fmaxf(m, __shfl_xor(m, 1));
        const float e = __expf(v - m);
        float ssum = e;
        ssum += __shfl_xor(ssum, 8); ssum += __shfl_xor(ssum, 4);
        ssum += __shfl_xor(ssum, 2); ssum += __shfl_xor(ssum, 1);
        wgt[rr][gg] = e / ssum;
    }
    __syncthreads();
    {
        const int c = tid;
        for (int r = 0; r < 8; ++r) {
            float acc = 0.f;
#pragma unroll
            for (int t = 0; t < Kv; ++t) {
                const long gi = (long)bq * Nv + idx_l[r][t];
                acc = fmaf(wgt[r][t], bf2f((unsigned)vb[gi * Cv + c]), acc);
            }
            // in-place: overwrite this block's own q rows with o (bf16)
            qb[(r0 + r) * Cv + c] = f2bf(acc);
        }
    }
}

extern "C" void kernel_launch(void* const* d_in, const int* in_sizes, int n_in,
                              void* d_out, int out_size, void* d_ws, size_t ws_size,
                              hipStream_t stream) {
    (void)in_sizes; (void)n_in; (void)out_size; (void)ws_size;
    const float* x      = (const float*)d_in[0];
    const float* pos    = (const float*)d_in[1];
    const float* Wq     = (const float*)d_in[2];
    const float* Wk     = (const float*)d_in[3];
    const float* Wv     = (const float*)d_in[4];
    const float* W1     = (const float*)d_in[5];
    const float* b1     = (const float*)d_in[6];
    const float* W2     = (const float*)d_in[7];
    const float* b2     = (const float*)d_in[8];
    const float* Wp     = (const float*)d_in[9];
    const float* bp     = (const float*)d_in[10];
    const float* gq     = (const float*)d_in[11];
    const float* betaq  = (const float*)d_in[12];
    const float* gkv    = (const float*)d_in[13];
    const float* betakv = (const float*)d_in[14];
    float* out = (float*)d_out;

    char* ws = (char*)d_ws;
    unsigned short* qb = (unsigned short*)(ws);               // 3 x 16 MiB bf16 q/k/v
    unsigned short* kb = (unsigned short*)(ws + 16777216);
    unsigned short* vb = (unsigned short*)(ws + 33554432);
    int*   idx   = (int*)  (ws + 50331648);                   // 2 MiB
    unsigned short* Bt = (unsigned short*)(ws + 52428800);    // 1024*256*2 = 512 KiB
    float* w2sum = (float*)(ws + 52953088);
    float* b2sum = (float*)(ws + 52953344);

    unsigned short* Aq  = (unsigned short*)d_out;             // d_out as scratch
    unsigned short* Akv = (unsigned short*)d_out + 8388608;

    hipLaunchKernelGGL(prep_kernel, dim3(1), dim3(64), 0, stream, W2, b2, w2sum, b2sum);
    hipLaunchKernelGGL(wcast_kernel, dim3(1024), dim3(256), 0, stream, Wq, Wk, Wv, Wp, Bt);
    hipLaunchKernelGGL(ln_cast_kernel, dim3(4096), dim3(256), 0, stream,
                       x, gq, betaq, gkv, betakv, Aq, Akv);
    hipLaunchKernelGGL(gemm_qkv_kernel, dim3(256, 6), dim3(256), 0, stream,
                       Aq, Akv, Bt, qb, kb, vb);
    hipLaunchKernelGGL(knn_kernel, dim3(1024), dim3(256), 0, stream, pos, idx);
    hipLaunchKernelGGL(attn_core_kernel, dim3(4096), dim3(256), 0, stream,
                       qb, kb, vb, idx, pos, W1, b1, w2sum, b2sum);
    // o (bf16, in qb) @ Wp^T + bp -> f32 out
    hipLaunchKernelGGL(gemm_proj_kernel, dim3(256, 2), dim3(256), 0, stream,
                       qb, Bt + 768 * 256, bp, out);
}